// Round 1
// baseline (5901.117 us; speedup 1.0000x reference)
//
#include <hip/hip_runtime.h>
#include <math.h>

// Problem constants
#define NB 8
#define NT 2048
#define NC 128
#define NLM 64
#define NS 4
// Q rows per batch = NT+1
#define QROWS 2049

__device__ __forceinline__ float tanh_fast(float x) {
  // tanh(x) = 1 - 2/(exp(2x)+1); exact limits at +-inf, no NaN for finite x
  float ex = __expf(2.f * x);
  return 1.f - 2.f / (ex + 1.f);
}

// K1: per 4 rows (b,t): z = x@W + b ; u = [cos,sin]*rs ; V = u @ phi_w
// stores V into Q[b][t+1][:]  (K2 cumsums in place)
__global__ __launch_bounds__(128) void k1_uv(
    const float* __restrict__ x, const float* __restrict__ W,
    const float* __restrict__ bias, const float* __restrict__ phiw,
    float* __restrict__ Q) {
  __shared__ float xs[4][128];
  __shared__ float us[4][256];
  const int j = threadIdx.x;
  const int bt0 = blockIdx.x * 4;
#pragma unroll
  for (int r = 0; r < 4; ++r) xs[r][j] = x[(bt0 + r) * NC + j];
  __syncthreads();
  float z0 = bias[j], z1 = z0, z2 = z0, z3 = z0;
  for (int k = 0; k < 128; ++k) {
    float w = W[k * 128 + j];
    z0 = fmaf(xs[0][k], w, z0);
    z1 = fmaf(xs[1][k], w, z1);
    z2 = fmaf(xs[2][k], w, z2);
    z3 = fmaf(xs[3][k], w, z3);
  }
  const float rs = 0.08838834764831845f;  // 1/sqrt(128)
  float sv, cv;
  sincosf(z0, &sv, &cv); us[0][j] = cv * rs; us[0][128 + j] = sv * rs;
  sincosf(z1, &sv, &cv); us[1][j] = cv * rs; us[1][128 + j] = sv * rs;
  sincosf(z2, &sv, &cv); us[2][j] = cv * rs; us[2][128 + j] = sv * rs;
  sincosf(z3, &sv, &cv); us[3][j] = cv * rs; us[3][128 + j] = sv * rs;
  __syncthreads();
  float a0 = 0.f, a1 = 0.f, a2 = 0.f, a3 = 0.f;
  for (int k = 0; k < 256; ++k) {
    float w = phiw[k * 128 + j];
    a0 = fmaf(us[0][k], w, a0);
    a1 = fmaf(us[1][k], w, a1);
    a2 = fmaf(us[2][k], w, a2);
    a3 = fmaf(us[3][k], w, a3);
  }
#pragma unroll
  for (int r = 0; r < 4; ++r) {
    int bt = bt0 + r;
    int b = bt >> 11, t = bt & 2047;
    float v = (r == 0) ? a0 : (r == 1) ? a1 : (r == 2) ? a2 : a3;
    Q[(b * QROWS + t + 1) * NC + j] = v;
  }
}

// K2: in-place exclusive-style cumsum: Q[b][0]=0; Q[b][tau] = sum_{i<tau} V[i]
__global__ __launch_bounds__(128) void k2_cumsum(float* __restrict__ Q) {
  const int b = blockIdx.x;
  const int c = threadIdx.x;
  float acc = 0.f;
  Q[(b * QROWS) * NC + c] = 0.f;
#pragma unroll 8
  for (int tau = 1; tau <= NT; ++tau) {
    float* p = Q + (b * QROWS + tau) * NC + c;
    acc += *p;
    *p = acc;
  }
}

// K3: sequential logZ scan + softmax weights pi.  One wave per (s,b) chain.
// piS layout: [(s*8+b)][ti][l]  (ti = 0-based output step, t = ti+1)
__global__ __launch_bounds__(64) void k3_logz(
    const float* __restrict__ logw, float* __restrict__ piS) {
  __shared__ float lz[QROWS];
  const int s = blockIdx.x >> 3, b = blockIdx.x & 7;
  const int l = threadIdx.x;
  const float lw = logw[s * NLM + l];
  if (l == 0) lz[0] = 0.f;
  __syncthreads();
  float* pib = piS + ((long)(s * 8 + b)) * NT * NLM;
  for (int t = 1; t <= NT; ++t) {
    int idx = t - 1 - l;
    float la = (idx >= 0) ? lw + lz[idx] : -INFINITY;
    float m = la;
#pragma unroll
    for (int off = 32; off; off >>= 1) m = fmaxf(m, __shfl_xor(m, off));
    float p = expf(la - m);
    float zs = p;
#pragma unroll
    for (int off = 32; off; off >>= 1) zs += __shfl_xor(zs, off);
    pib[(t - 1) * NLM + l] = p / zs;
    if (l == 0) lz[t] = m + logf(zs);
    __syncthreads();
  }
}

// K4: e[s,b,ti,c] = sum_l pi[s,b,ti,l] * tanh((Q[ti+1]-Q[ti-l])/(l+9) + phi_b)
// writes into eq buffer (later overwritten in place by q in K5)
__global__ __launch_bounds__(256) void k4_e(
    const float* __restrict__ Q, const float* __restrict__ piS,
    const float* __restrict__ phib, float* __restrict__ eq) {
  __shared__ float Qw[96][128];
  const int b = blockIdx.x;
  const int t0 = blockIdx.y * 32;
  const int tid = threadIdx.x;
  for (int i = tid; i < 96 * 128; i += 256) {
    int r = i >> 7, c = i & 127;
    int tau = t0 - 63 + r;
    Qw[r][c] = (tau >= 0) ? Q[(b * QROWS + tau) * NC + c] : 0.f;
  }
  __syncthreads();
  const int c = tid & 127, th = tid >> 7;
  const float pb = phib[c];
  for (int tt = th; tt < 32; tt += 2) {
    const int ti = t0 + tt;
    const float Qt = Qw[tt + 64][c];
    const float* p0 = piS + (long)(0 * 8 + b) * NT * NLM + (long)ti * NLM;
    const float* p1 = p0 + (long)8 * NT * NLM;
    const float* p2 = p1 + (long)8 * NT * NLM;
    const float* p3 = p2 + (long)8 * NT * NLM;
    float a0 = 0.f, a1 = 0.f, a2 = 0.f, a3 = 0.f;
#pragma unroll
    for (int l = 0; l < 64; ++l) {
      float sm = (Qt - Qw[tt + 63 - l][c]) * (1.f / (float)(l + 9)) + pb;
      float v = tanh_fast(sm);
      a0 = fmaf(p0[l], v, a0);
      a1 = fmaf(p1[l], v, a1);
      a2 = fmaf(p2[l], v, a2);
      a3 = fmaf(p3[l], v, a3);
    }
    eq[((long)(0 * 8 + b) * NT + ti) * NC + c] = a0;
    eq[((long)(1 * 8 + b) * NT + ti) * NC + c] = a1;
    eq[((long)(2 * 8 + b) * NT + ti) * NC + c] = a2;
    eq[((long)(3 * 8 + b) * NT + ti) * NC + c] = a3;
  }
}

// K5: blocks 0..31: q-scan (q_t = sum_L pi_L q_{t-L} + e_t), in-place e->q.
//     blocks 32..63: k-scan (k_t = sum_L pi_L (k_{t-L}+1)) via wave butterfly.
__global__ __launch_bounds__(128) void k5_scan(
    const float* __restrict__ piS, float* __restrict__ eq,
    float* __restrict__ kout) {
  if (blockIdx.x < 32) {
    const int sb = blockIdx.x;
    const int c = threadIdx.x;
    const float* pb = piS + (long)sb * NT * NLM;
    float* qb = eq + (long)sb * NT * NC;
    float h[64];
#pragma unroll
    for (int i = 0; i < 64; ++i) h[i] = 0.f;
    for (int tb = 0; tb < NT; tb += 64) {
#pragma unroll
      for (int j = 0; j < 64; ++j) {
        const int ti = tb + j;
        const float* pp = pb + (long)ti * NLM;  // uniform -> scalar loads
        float acc0 = qb[ti * NC + c];           // e_t (read before overwrite)
        float acc1 = 0.f, acc2 = 0.f, acc3 = 0.f;
#pragma unroll
        for (int l = 0; l < 64; l += 4) {
          acc0 = fmaf(pp[l + 0], h[(j - l - 1) & 63], acc0);
          acc1 = fmaf(pp[l + 1], h[(j - l - 2) & 63], acc1);
          acc2 = fmaf(pp[l + 2], h[(j - l - 3) & 63], acc2);
          acc3 = fmaf(pp[l + 3], h[(j - l - 4) & 63], acc3);
        }
        float qv = (acc0 + acc1) + (acc2 + acc3);
        h[j] = qv;
        qb[ti * NC + c] = qv;
      }
    }
  } else {
    const int sb = blockIdx.x - 32;
    const int l = threadIdx.x;
    __shared__ float pis[64 * 64];
    const float* pb = piS + (long)sb * NT * NLM;
    float* kb = kout + (long)sb * NT;
    float kh = 0.f;  // lane l holds k[ti-1-l] (0 if out of range)
    for (int tb = 0; tb < NT; tb += 64) {
      for (int i = threadIdx.x; i < 4096; i += 128) pis[i] = pb[(long)tb * NLM + i];
      __syncthreads();
      if (l < 64) {
        for (int j = 0; j < 64; ++j) {
          float val = pis[j * 64 + l] * (kh + 1.f);
#pragma unroll
          for (int off = 32; off; off >>= 1) val += __shfl_xor(val, off);
          if (l == 0) kb[tb + j] = val;
          float up = __shfl_up(kh, 1);
          kh = (l == 0) ? val : up;
        }
      }
      __syncthreads();
    }
  }
}

// K6: rep = (q + 16*anchor)/(k+16) * (k/(k+16)); out = rep_flat @ mix_w + mix_b
__global__ __launch_bounds__(128) void k6_mix(
    const float* __restrict__ q, const float* __restrict__ kout,
    const float* __restrict__ anchor, const float* __restrict__ mixw,
    const float* __restrict__ mixb, float* __restrict__ out) {
  __shared__ float rsdata[8][512];
  const int b = blockIdx.x;
  const int t0 = blockIdx.y * 8;
  const int tid = threadIdx.x;
  for (int i = tid; i < 8 * 512; i += 128) {
    int r = i >> 9, sc = i & 511;
    int s = sc >> 7, c = sc & 127;
    int ti = t0 + r;
    float qv = q[((long)(s * 8 + b) * NT + ti) * NC + c];
    float kv = kout[(long)(s * 8 + b) * NT + ti];
    float d1 = 1.f / (kv + 16.f);
    rsdata[r][sc] = (qv + 16.f * anchor[sc]) * d1 * (kv * d1);
  }
  __syncthreads();
  const int co = tid;
  float mb = mixb[co];
  float acc[8];
#pragma unroll
  for (int r = 0; r < 8; ++r) acc[r] = mb;
  for (int kk = 0; kk < 512; ++kk) {
    float w = mixw[kk * 128 + co];
#pragma unroll
    for (int r = 0; r < 8; ++r) acc[r] = fmaf(rsdata[r][kk], w, acc[r]);
  }
#pragma unroll
  for (int r = 0; r < 8; ++r) out[((long)b * NT + t0 + r) * NC + co] = acc[r];
}

extern "C" void kernel_launch(void* const* d_in, const int* in_sizes, int n_in,
                              void* d_out, int out_size, void* d_ws, size_t ws_size,
                              hipStream_t stream) {
  const float* x = (const float*)d_in[0];
  const float* W = (const float*)d_in[1];
  const float* bias = (const float*)d_in[2];
  const float* phiw = (const float*)d_in[3];
  const float* phib = (const float*)d_in[4];
  const float* anchor = (const float*)d_in[5];
  const float* logw = (const float*)d_in[6];
  const float* mixw = (const float*)d_in[7];
  const float* mixb = (const float*)d_in[8];
  float* out = (float*)d_out;

  float* ws = (float*)d_ws;
  float* Q = ws;                                // 8*2049*128   = 2,098,176 f
  float* piS = Q + (long)NB * QROWS * NC;       // 32*2048*64   = 4,194,304 f
  float* eq = piS + (long)NS * NB * NT * NLM;   // 32*2048*128  = 8,388,608 f
  float* kk = eq + (long)NS * NB * NT * NC;     // 32*2048      =    65,536 f
  // total ~59 MB of workspace

  hipLaunchKernelGGL(k1_uv, dim3(NB * NT / 4), dim3(128), 0, stream, x, W, bias, phiw, Q);
  hipLaunchKernelGGL(k2_cumsum, dim3(NB), dim3(128), 0, stream, Q);
  hipLaunchKernelGGL(k3_logz, dim3(NS * NB), dim3(64), 0, stream, logw, piS);
  hipLaunchKernelGGL(k4_e, dim3(NB, NT / 32), dim3(256), 0, stream, Q, piS, phib, eq);
  hipLaunchKernelGGL(k5_scan, dim3(64), dim3(128), 0, stream, piS, eq, kk);
  hipLaunchKernelGGL(k6_mix, dim3(NB, NT / 8), dim3(128), 0, stream, eq, kk, anchor, mixw, mixb, out);
}

// Round 2
// 646.868 us; speedup vs baseline: 9.1226x; 9.1226x over previous
//
#include <hip/hip_runtime.h>
#include <math.h>

// Problem constants
#define NB 8
#define NT 2048
#define NC 128
#define NLM 64
#define NS 4
#define QROWS 2049
#define NCH 32  // 2048 / 64 chunks

__device__ __forceinline__ float tanh_fast(float x) {
  float ex = __expf(2.f * x);
  return 1.f - 2.f / (ex + 1.f);
}

// ---------------------------------------------------------------------------
// Tiled 64-step local linear scan (forward substitution), all indices
// compile-time so q[4][16] stays in VGPRs (the round-1 k5 spilled h[64]
// to scratch: VGPR_Count=48 + 15 GB/s scratch traffic = 4.4 ms).
//   q[t] = D(t) + sum_{t'<t} P(t, t-t'-1) * q[t']
// ---------------------------------------------------------------------------
template <typename PF, typename DF>
__device__ __forceinline__ void tri_scan64(PF P, DF D, float q[4][16]) {
#pragma unroll
  for (int tau = 0; tau < 4; ++tau) {
    float acc[16];
#pragma unroll
    for (int i = 0; i < 16; ++i) acc[i] = D(tau * 16 + i);
    // cross-tile dense blocks
#pragma unroll
    for (int p = 0; p < 4; ++p) {
      if (p < tau) {
#pragma unroll
        for (int i = 0; i < 16; ++i) {
          const int t = tau * 16 + i;
#pragma unroll
          for (int i2 = 0; i2 < 16; ++i2) {
            acc[i] = fmaf(P(t, t - (p * 16 + i2) - 1), q[p][i2], acc[i]);
          }
        }
      }
    }
    // within-tile sequential (triangular)
#pragma unroll
    for (int i = 0; i < 16; ++i) {
      const int t = tau * 16 + i;
#pragma unroll
      for (int i2 = 0; i2 < 16; ++i2) {
        if (i2 < i) acc[i] = fmaf(P(t, i - i2 - 1), q[tau][i2], acc[i]);
      }
      q[tau][i] = acc[i];
    }
  }
}

// K1: per 4 rows (b,t): z = x@W + b ; u = [cos,sin]/sqrt(dh) ; V = u @ phi_w
__global__ __launch_bounds__(128) void k1_uv(
    const float* __restrict__ x, const float* __restrict__ W,
    const float* __restrict__ bias, const float* __restrict__ phiw,
    float* __restrict__ Q) {
  __shared__ float xs[4][128];
  __shared__ float us[4][256];
  const int j = threadIdx.x;
  const int bt0 = blockIdx.x * 4;
#pragma unroll
  for (int r = 0; r < 4; ++r) xs[r][j] = x[(bt0 + r) * NC + j];
  __syncthreads();
  float z0 = bias[j], z1 = z0, z2 = z0, z3 = z0;
  for (int k = 0; k < 128; ++k) {
    float w = W[k * 128 + j];
    z0 = fmaf(xs[0][k], w, z0);
    z1 = fmaf(xs[1][k], w, z1);
    z2 = fmaf(xs[2][k], w, z2);
    z3 = fmaf(xs[3][k], w, z3);
  }
  const float rs = 0.08838834764831845f;
  float sv, cv;
  sincosf(z0, &sv, &cv); us[0][j] = cv * rs; us[0][128 + j] = sv * rs;
  sincosf(z1, &sv, &cv); us[1][j] = cv * rs; us[1][128 + j] = sv * rs;
  sincosf(z2, &sv, &cv); us[2][j] = cv * rs; us[2][128 + j] = sv * rs;
  sincosf(z3, &sv, &cv); us[3][j] = cv * rs; us[3][128 + j] = sv * rs;
  __syncthreads();
  float a0 = 0.f, a1 = 0.f, a2 = 0.f, a3 = 0.f;
  for (int k = 0; k < 256; ++k) {
    float w = phiw[k * 128 + j];
    a0 = fmaf(us[0][k], w, a0);
    a1 = fmaf(us[1][k], w, a1);
    a2 = fmaf(us[2][k], w, a2);
    a3 = fmaf(us[3][k], w, a3);
  }
#pragma unroll
  for (int r = 0; r < 4; ++r) {
    int bt = bt0 + r;
    int b = bt >> 11, t = bt & 2047;
    float v = (r == 0) ? a0 : (r == 1) ? a1 : (r == 2) ? a2 : a3;
    Q[(b * QROWS + t + 1) * NC + j] = v;
  }
}

// K2 (chunk-parallel cumsum): a) per-chunk sums, b) per-b scan, c) fixup
__global__ __launch_bounds__(128) void k2a_sums(const float* __restrict__ Q,
                                                float* __restrict__ S2) {
  const int b = blockIdx.x, ch = blockIdx.y, c = threadIdx.x;
  float acc = 0.f;
#pragma unroll 8
  for (int i = 0; i < 64; ++i) acc += Q[(b * QROWS + ch * 64 + 1 + i) * NC + c];
  S2[(b * NCH + ch) * NC + c] = acc;
}

__global__ __launch_bounds__(128) void k2b_scan(float* __restrict__ S2) {
  const int b = blockIdx.x, c = threadIdx.x;
  float acc = 0.f;
  for (int ch = 0; ch < NCH; ++ch) {
    float* p = S2 + (b * NCH + ch) * NC + c;
    float v = *p;
    *p = acc;  // exclusive
    acc += v;
  }
}

__global__ __launch_bounds__(128) void k2c_fix(float* __restrict__ Q,
                                               const float* __restrict__ S2) {
  const int b = blockIdx.x, ch = blockIdx.y, c = threadIdx.x;
  if (ch == 0) Q[(b * QROWS) * NC + c] = 0.f;
  float run = S2[(b * NCH + ch) * NC + c];
#pragma unroll 4
  for (int i = 0; i < 64; ++i) {
    float* p = Q + (b * QROWS + ch * 64 + 1 + i) * NC + c;
    run += *p;
    *p = run;
  }
}

// K3a: per-s unit-response matrix of the Z recurrence (linear domain).
// MT[s][j][t] = response at step t to Z-history one-hot at lookback j+1.
__global__ __launch_bounds__(64) void k3a_m(const float* __restrict__ logw,
                                            float* __restrict__ mT) {
  const int s = blockIdx.x;
  __shared__ float wx[64];
  const int j = threadIdx.x;
  wx[j] = __expf(logw[s * NLM + j]);
  __syncthreads();
  float q[4][16];
  tri_scan64([&](int t, int l) { return wx[l]; },
             [&](int t) { int l = t + j; return (l < 64) ? wx[l] : 0.f; }, q);
  float* mb = mT + ((long)s * 64 + j) * 64;
#pragma unroll
  for (int tau = 0; tau < 4; ++tau)
#pragma unroll
    for (int i = 0; i < 16; ++i) mb[tau * 16 + i] = q[tau][i];
}

// K3b: 32 sequential chunk-steps of the rescaled linear logZ evolution, per s.
__global__ __launch_bounds__(64) void k3b_logz(const float* __restrict__ mT,
                                               float* __restrict__ logZt) {
  const int s = blockIdx.x;
  const int t = threadIdx.x;
  __shared__ float Zr[64];
  Zr[t] = (t == 0) ? 1.f : 0.f;
  if (t == 0) logZt[s * QROWS] = 0.f;
  float off = 0.f;
  __syncthreads();
  const float* mb = mT + (long)s * 64 * 64;  // [j][t]
  for (int ch = 0; ch < NCH; ++ch) {
    float acc = 0.f;
#pragma unroll 8
    for (int j = 0; j < 64; ++j) acc = fmaf(mb[j * 64 + t], Zr[j], acc);
    logZt[s * QROWS + ch * 64 + 1 + t] = logf(acc) + off;
    float mx = acc;
#pragma unroll
    for (int o = 32; o; o >>= 1) mx = fmaxf(mx, __shfl_xor(mx, o));
    __syncthreads();
    Zr[63 - t] = acc / mx;
    off += logf(mx);
    __syncthreads();
  }
}

// K3c: pi[s][ti][l] = softmax_l(lw[l] + logZ[ti-l]) — fully parallel.
__global__ __launch_bounds__(256) void k3c_pi(const float* __restrict__ logw,
                                              const float* __restrict__ logZt,
                                              float* __restrict__ pi) {
  const int s = blockIdx.y;
  const int ti = blockIdx.x * 4 + (threadIdx.x >> 6);
  const int l = threadIdx.x & 63;
  float la = -INFINITY;
  if (ti - l >= 0) la = logw[s * NLM + l] + logZt[s * QROWS + ti - l];
  float m = la;
#pragma unroll
  for (int o = 32; o; o >>= 1) m = fmaxf(m, __shfl_xor(m, o));
  float p = __expf(la - m);
  float zs = p;
#pragma unroll
  for (int o = 32; o; o >>= 1) zs += __shfl_xor(zs, o);
  pi[((long)s * NT + ti) * NLM + l] = p / zs;
}

// K4: e[s,b,ti,c] = sum_l pi[s,ti,l] * tanh((Q[ti+1]-Q[ti-l])/(l+9) + phi_b)
__global__ __launch_bounds__(256) void k4_e(
    const float* __restrict__ Q, const float* __restrict__ pi,
    const float* __restrict__ phib, float* __restrict__ eq) {
  __shared__ float Qw[96][128];
  const int b = blockIdx.x;
  const int t0 = blockIdx.y * 32;
  const int tid = threadIdx.x;
  for (int i = tid; i < 96 * 128; i += 256) {
    int r = i >> 7, c = i & 127;
    int tau = t0 - 63 + r;
    Qw[r][c] = (tau >= 0) ? Q[(b * QROWS + tau) * NC + c] : 0.f;
  }
  __syncthreads();
  const int c = tid & 127, th = tid >> 7;
  const float pb = phib[c];
  for (int tt = th; tt < 32; tt += 2) {
    const int ti = t0 + tt;
    const float Qt = Qw[tt + 64][c];
    const float* p0 = pi + (long)ti * NLM;
    const float* p1 = p0 + (long)NT * NLM;
    const float* p2 = p1 + (long)NT * NLM;
    const float* p3 = p2 + (long)NT * NLM;
    float a0 = 0.f, a1 = 0.f, a2 = 0.f, a3 = 0.f;
#pragma unroll
    for (int l = 0; l < 64; ++l) {
      float sm = (Qt - Qw[tt + 63 - l][c]) * (1.f / (float)(l + 9)) + pb;
      float v = tanh_fast(sm);
      a0 = fmaf(p0[l], v, a0);
      a1 = fmaf(p1[l], v, a1);
      a2 = fmaf(p2[l], v, a2);
      a3 = fmaf(p3[l], v, a3);
    }
    eq[((long)(0 * 8 + b) * NT + ti) * NC + c] = a0;
    eq[((long)(1 * 8 + b) * NT + ti) * NC + c] = a1;
    eq[((long)(2 * 8 + b) * NT + ti) * NC + c] = a2;
    eq[((long)(3 * 8 + b) * NT + ti) * NC + c] = a3;
  }
}

// K5a-basis: per (s,chunk) unit-response CoefT[s][ch][j][t] + local k (e=1).
__global__ __launch_bounds__(128) void k5a_basis(const float* __restrict__ pi,
                                                 float* __restrict__ coefT,
                                                 float* __restrict__ klocal) {
  const int s = blockIdx.x, ch = blockIdx.y;
  const int tid = threadIdx.x;
  const float* pib = pi + ((long)s * NT + ch * 64) * NLM;
  float q[4][16];
  if (tid < 64) {
    const int j = tid;
    tri_scan64([&](int t, int l) { return pib[t * 64 + l]; },
               [&](int t) { int l = t + j; return (l < 64) ? pib[t * 64 + l] : 0.f; }, q);
    float* ct = coefT + (((long)s * NCH + ch) * 64 + j) * 64;
#pragma unroll
    for (int tau = 0; tau < 4; ++tau)
#pragma unroll
      for (int i = 0; i < 16; ++i) ct[tau * 16 + i] = q[tau][i];
  } else if (tid == 64) {
    tri_scan64([&](int t, int l) { return pib[t * 64 + l]; },
               [&](int t) { return 1.f; }, q);
    float* kl = klocal + ((long)s * NCH + ch) * 64;
#pragma unroll
    for (int tau = 0; tau < 4; ++tau)
#pragma unroll
      for (int i = 0; i < 16; ++i) kl[tau * 16 + i] = q[tau][i];
  }
}

// K5a-data: per (s,b,chunk) local scan with zero history, e -> qlocal in place.
__global__ __launch_bounds__(128) void k5a_data(const float* __restrict__ pi,
                                                float* __restrict__ eq) {
  const int sb = blockIdx.x;  // s*8+b
  const int s = sb >> 3;
  const int ch = blockIdx.y;
  const int c = threadIdx.x;
  const float* pib = pi + ((long)s * NT + ch * 64) * NLM;
  float* qb = eq + ((long)sb * NT + ch * 64) * NC + c;
  float q[4][16];
  tri_scan64([&](int t, int l) { return pib[t * 64 + l]; },
             [&](int t) { return qb[t * NC]; }, q);
#pragma unroll
  for (int tau = 0; tau < 4; ++tau)
#pragma unroll
    for (int i = 0; i < 16; ++i) qb[(tau * 16 + i) * NC] = q[tau][i];
}

// K5b-q: sequential cross-chunk combine per (s,b): 32 steps of
//        qfull[t][c] = qlocal[t][c] + sum_j Coef[t][j] * H[j][c]
__global__ __launch_bounds__(512) void k5b_q(const float* __restrict__ coefT,
                                             float* __restrict__ eq) {
  __shared__ float H[2][64][128];
  const int sb = blockIdx.x;
  const int s = sb >> 3;
  const int tid = threadIdx.x;
  const int c = tid & 127;
  const int tqu = __builtin_amdgcn_readfirstlane(tid >> 7);  // wave-uniform
  for (int i = tid; i < 64 * 128; i += 512) H[0][i >> 7][i & 127] = 0.f;
  __syncthreads();
  int cur = 0;
  for (int ch = 0; ch < NCH; ++ch) {
    const float* ct = coefT + ((long)s * NCH + ch) * 64 * 64 + tqu * 16;
    float acc[16];
#pragma unroll
    for (int i = 0; i < 16; ++i) acc[i] = 0.f;
#pragma unroll 4
    for (int j = 0; j < 64; ++j) {
      float hj = H[cur][j][c];
      const float* cr = ct + j * 64;  // uniform -> s_load
#pragma unroll
      for (int i = 0; i < 16; ++i) acc[i] = fmaf(cr[i], hj, acc[i]);
    }
    float* qb = eq + ((long)sb * NT + ch * 64) * NC + c;
#pragma unroll
    for (int i = 0; i < 16; ++i) {
      const int t = tqu * 16 + i;
      float v = acc[i] + qb[t * NC];
      qb[t * NC] = v;
      H[cur ^ 1][63 - t][c] = v;
    }
    __syncthreads();
    cur ^= 1;
  }
}

// K5b-k: same combine for the scalar k chain, per s (batch-independent).
__global__ __launch_bounds__(64) void k5b_k(const float* __restrict__ coefT,
                                            const float* __restrict__ klocal,
                                            float* __restrict__ kout) {
  __shared__ float Hk[2][64];
  const int s = blockIdx.x;
  const int t = threadIdx.x;
  Hk[0][t] = 0.f;
  __syncthreads();
  int cur = 0;
  for (int ch = 0; ch < NCH; ++ch) {
    const float* ct = coefT + ((long)s * NCH + ch) * 64 * 64;
    float acc = klocal[((long)s * NCH + ch) * 64 + t];
#pragma unroll 8
    for (int j = 0; j < 64; ++j) acc = fmaf(ct[j * 64 + t], Hk[cur][j], acc);
    kout[s * NT + ch * 64 + t] = acc;
    __syncthreads();
    Hk[cur ^ 1][63 - t] = acc;
    __syncthreads();
    cur ^= 1;
  }
}

// K6: rep = (q + 16*anchor)/(k+16) * (k/(k+16)); out = rep_flat @ mix_w + mix_b
__global__ __launch_bounds__(128) void k6_mix(
    const float* __restrict__ q, const float* __restrict__ kout,
    const float* __restrict__ anchor, const float* __restrict__ mixw,
    const float* __restrict__ mixb, float* __restrict__ out) {
  __shared__ float rsdata[8][512];
  const int b = blockIdx.x;
  const int t0 = blockIdx.y * 8;
  const int tid = threadIdx.x;
  for (int i = tid; i < 8 * 512; i += 128) {
    int r = i >> 9, sc = i & 511;
    int s = sc >> 7, c = sc & 127;
    int ti = t0 + r;
    float qv = q[((long)(s * 8 + b) * NT + ti) * NC + c];
    float kv = kout[s * NT + ti];
    float d1 = 1.f / (kv + 16.f);
    rsdata[r][sc] = (qv + 16.f * anchor[sc]) * d1 * (kv * d1);
  }
  __syncthreads();
  const int co = tid;
  float mb = mixb[co];
  float acc[8];
#pragma unroll
  for (int r = 0; r < 8; ++r) acc[r] = mb;
  for (int kk = 0; kk < 512; ++kk) {
    float w = mixw[kk * 128 + co];
#pragma unroll
    for (int r = 0; r < 8; ++r) acc[r] = fmaf(rsdata[r][kk], w, acc[r]);
  }
#pragma unroll
  for (int r = 0; r < 8; ++r) out[((long)b * NT + t0 + r) * NC + co] = acc[r];
}

extern "C" void kernel_launch(void* const* d_in, const int* in_sizes, int n_in,
                              void* d_out, int out_size, void* d_ws, size_t ws_size,
                              hipStream_t stream) {
  const float* x = (const float*)d_in[0];
  const float* W = (const float*)d_in[1];
  const float* bias = (const float*)d_in[2];
  const float* phiw = (const float*)d_in[3];
  const float* phib = (const float*)d_in[4];
  const float* anchor = (const float*)d_in[5];
  const float* logw = (const float*)d_in[6];
  const float* mixw = (const float*)d_in[7];
  const float* mixb = (const float*)d_in[8];
  float* out = (float*)d_out;

  float* ws = (float*)d_ws;
  float* Q = ws;                                  // 8*2049*128 = 2,098,176
  float* pi = Q + (long)NB * QROWS * NC;          // 4*2048*64  =   524,288
  float* eq = pi + (long)NS * NT * NLM;           // 32*2048*128= 8,388,608
  float* coefT = eq + (long)NS * NB * NT * NC;    // 4*32*64*64 =   524,288
  float* klocal = coefT + (long)NS * NCH * 64 * 64;  //            8,192
  float* kout = klocal + (long)NS * NCH * 64;        //            8,192
  float* logZt = kout + (long)NS * NT;               //            8,196
  float* mT = logZt + (long)NS * QROWS;              //           16,384
  float* S2 = mT + (long)NS * 64 * 64;               //           32,768
  // total ~46.4 MB

  hipLaunchKernelGGL(k1_uv, dim3(NB * NT / 4), dim3(128), 0, stream, x, W, bias, phiw, Q);
  hipLaunchKernelGGL(k2a_sums, dim3(NB, NCH), dim3(128), 0, stream, Q, S2);
  hipLaunchKernelGGL(k2b_scan, dim3(NB), dim3(128), 0, stream, S2);
  hipLaunchKernelGGL(k2c_fix, dim3(NB, NCH), dim3(128), 0, stream, Q, S2);
  hipLaunchKernelGGL(k3a_m, dim3(NS), dim3(64), 0, stream, logw, mT);
  hipLaunchKernelGGL(k3b_logz, dim3(NS), dim3(64), 0, stream, mT, logZt);
  hipLaunchKernelGGL(k3c_pi, dim3(NT / 4, NS), dim3(256), 0, stream, logw, logZt, pi);
  hipLaunchKernelGGL(k4_e, dim3(NB, NT / 32), dim3(256), 0, stream, Q, pi, phib, eq);
  hipLaunchKernelGGL(k5a_basis, dim3(NS, NCH), dim3(128), 0, stream, pi, coefT, klocal);
  hipLaunchKernelGGL(k5a_data, dim3(NS * NB, NCH), dim3(128), 0, stream, pi, eq);
  hipLaunchKernelGGL(k5b_q, dim3(NS * NB), dim3(512), 0, stream, coefT, eq);
  hipLaunchKernelGGL(k5b_k, dim3(NS), dim3(64), 0, stream, coefT, klocal, kout);
  hipLaunchKernelGGL(k6_mix, dim3(NB, NT / 8), dim3(128), 0, stream, eq, kout, anchor, mixw, mixb, out);
}

// Round 3
// 535.939 us; speedup vs baseline: 11.0108x; 1.2070x over previous
//
#include <hip/hip_runtime.h>
#include <math.h>

// Problem constants
#define NB 8
#define NT 2048
#define NC 128
#define NLM 64
#define NS 4
#define QROWS 2049
#define NCH 32  // 2048 / 64 chunks

__device__ __forceinline__ float tanh_fast(float x) {
  float ex = __expf(2.f * x);
  return 1.f - 2.f / (ex + 1.f);
}

// ---------------------------------------------------------------------------
// Tiled 64-step local linear scan (forward substitution); all indices
// compile-time so q[4][16] stays in VGPRs.
//   q[t] = D(t) + sum_{t'<t} P(t, t-t'-1) * q[t']
// ---------------------------------------------------------------------------
template <typename PF, typename DF>
__device__ __forceinline__ void tri_scan64(PF P, DF D, float q[4][16]) {
#pragma unroll
  for (int tau = 0; tau < 4; ++tau) {
    float acc[16];
#pragma unroll
    for (int i = 0; i < 16; ++i) acc[i] = D(tau * 16 + i);
#pragma unroll
    for (int p = 0; p < 4; ++p) {
      if (p < tau) {
#pragma unroll
        for (int i = 0; i < 16; ++i) {
          const int t = tau * 16 + i;
#pragma unroll
          for (int i2 = 0; i2 < 16; ++i2) {
            acc[i] = fmaf(P(t, t - (p * 16 + i2) - 1), q[p][i2], acc[i]);
          }
        }
      }
    }
#pragma unroll
    for (int i = 0; i < 16; ++i) {
      const int t = tau * 16 + i;
#pragma unroll
      for (int i2 = 0; i2 < 16; ++i2) {
        if (i2 < i) acc[i] = fmaf(P(t, i - i2 - 1), q[tau][i2], acc[i]);
      }
      q[tau][i] = acc[i];
    }
  }
}

// K1: per 8 rows (b,t): z = x@W + b ; u = [cos,sin]/sqrt(dh) ; V = u @ phi_w
__global__ __launch_bounds__(128) void k1_uv(
    const float* __restrict__ x, const float* __restrict__ W,
    const float* __restrict__ bias, const float* __restrict__ phiw,
    float* __restrict__ Q) {
  __shared__ float xs[8][128];
  __shared__ float us[8][256];
  const int j = threadIdx.x;
  const int bt0 = blockIdx.x * 8;
#pragma unroll
  for (int r = 0; r < 8; ++r) xs[r][j] = x[(bt0 + r) * NC + j];
  __syncthreads();
  float z[8];
  const float bj = bias[j];
#pragma unroll
  for (int r = 0; r < 8; ++r) z[r] = bj;
  for (int k = 0; k < 128; ++k) {
    float w = W[k * 128 + j];
#pragma unroll
    for (int r = 0; r < 8; ++r) z[r] = fmaf(xs[r][k], w, z[r]);
  }
  const float rs = 0.08838834764831845f;  // 1/sqrt(128)
#pragma unroll
  for (int r = 0; r < 8; ++r) {
    float sv, cv;
    sincosf(z[r], &sv, &cv);
    us[r][j] = cv * rs;
    us[r][128 + j] = sv * rs;
  }
  __syncthreads();
  float a[8];
#pragma unroll
  for (int r = 0; r < 8; ++r) a[r] = 0.f;
  for (int k = 0; k < 256; ++k) {
    float w = phiw[k * 128 + j];
#pragma unroll
    for (int r = 0; r < 8; ++r) a[r] = fmaf(us[r][k], w, a[r]);
  }
#pragma unroll
  for (int r = 0; r < 8; ++r) {
    int bt = bt0 + r;
    int b = bt >> 11, t = bt & 2047;
    Q[(b * QROWS + t + 1) * NC + j] = a[r];
  }
}

// K2 (chunk-parallel cumsum): a) per-chunk sums, b) per-b scan, c) fixup
__global__ __launch_bounds__(128) void k2a_sums(const float* __restrict__ Q,
                                                float* __restrict__ S2) {
  const int b = blockIdx.x, ch = blockIdx.y, c = threadIdx.x;
  float acc = 0.f;
#pragma unroll 8
  for (int i = 0; i < 64; ++i) acc += Q[(b * QROWS + ch * 64 + 1 + i) * NC + c];
  S2[(b * NCH + ch) * NC + c] = acc;
}

__global__ __launch_bounds__(128) void k2b_scan(float* __restrict__ S2) {
  const int b = blockIdx.x, c = threadIdx.x;
  float acc = 0.f;
  for (int ch = 0; ch < NCH; ++ch) {
    float* p = S2 + (b * NCH + ch) * NC + c;
    float v = *p;
    *p = acc;  // exclusive
    acc += v;
  }
}

__global__ __launch_bounds__(128) void k2c_fix(float* __restrict__ Q,
                                               const float* __restrict__ S2) {
  const int b = blockIdx.x, ch = blockIdx.y, c = threadIdx.x;
  if (ch == 0) Q[(b * QROWS) * NC + c] = 0.f;
  float run = S2[(b * NCH + ch) * NC + c];
#pragma unroll 4
  for (int i = 0; i < 64; ++i) {
    float* p = Q + (b * QROWS + ch * 64 + 1 + i) * NC + c;
    run += *p;
    *p = run;
  }
}

// K3ab fused: unit-response matrix mT of the Z recurrence (LDS) + 32
// sequential chunk-steps of the rescaled linear logZ evolution. Per s.
__global__ __launch_bounds__(64) void k3ab_logz(const float* __restrict__ logw,
                                                float* __restrict__ logZt) {
  const int s = blockIdx.x;
  const int j = threadIdx.x;  // doubles as t in phase 2
  __shared__ float wx[64];
  __shared__ float mTs[64][65];  // [j][t], padded (writes are row-per-lane)
  __shared__ float Zr[64];
  wx[j] = __expf(logw[s * NLM + j]);
  __syncthreads();
  float q[4][16];
  tri_scan64([&](int t, int l) { return wx[l]; },
             [&](int t) { int l = t + j; return (l < 64) ? wx[l] : 0.f; }, q);
#pragma unroll
  for (int tau = 0; tau < 4; ++tau)
#pragma unroll
    for (int i = 0; i < 16; ++i) mTs[j][tau * 16 + i] = q[tau][i];
  // phase 2
  const int t = j;
  Zr[t] = (t == 0) ? 1.f : 0.f;
  if (t == 0) logZt[s * QROWS] = 0.f;
  float off = 0.f;
  __syncthreads();
  for (int ch = 0; ch < NCH; ++ch) {
    float acc = 0.f;
#pragma unroll 8
    for (int jj = 0; jj < 64; ++jj) acc = fmaf(mTs[jj][t], Zr[jj], acc);
    logZt[s * QROWS + ch * 64 + 1 + t] = logf(acc) + off;
    float mx = acc;
#pragma unroll
    for (int o = 32; o; o >>= 1) mx = fmaxf(mx, __shfl_xor(mx, o));
    __syncthreads();
    Zr[63 - t] = acc / mx;
    off += logf(mx);
    __syncthreads();
  }
}

// K3c: pi[s][ti][l] = softmax_l(lw[l] + logZ[ti-l]) — fully parallel.
__global__ __launch_bounds__(256) void k3c_pi(const float* __restrict__ logw,
                                              const float* __restrict__ logZt,
                                              float* __restrict__ pi) {
  const int s = blockIdx.y;
  const int ti = blockIdx.x * 4 + (threadIdx.x >> 6);
  const int l = threadIdx.x & 63;
  float la = -INFINITY;
  if (ti - l >= 0) la = logw[s * NLM + l] + logZt[s * QROWS + ti - l];
  float m = la;
#pragma unroll
  for (int o = 32; o; o >>= 1) m = fmaxf(m, __shfl_xor(m, o));
  float p = __expf(la - m);
  float zs = p;
#pragma unroll
  for (int o = 32; o; o >>= 1) zs += __shfl_xor(zs, o);
  pi[((long)s * NT + ti) * NLM + l] = p / zs;
}

// K4: e[s,b,ti,c] = sum_l pi[s,ti,l] * tanh((Q[ti+1]-Q[ti-l])/(l+9) + phi_b)
// pi tiles staged in LDS (round-2 version read pi via serialized wave-uniform
// global loads).
__global__ __launch_bounds__(256) void k4_e(
    const float* __restrict__ Q, const float* __restrict__ pi,
    const float* __restrict__ phib, float* __restrict__ eq) {
  __shared__ float Qw[96][128];                    // 48 KB
  __shared__ __align__(16) float ps[4][32][64];    // 32 KB
  const int b = blockIdx.x;
  const int t0 = blockIdx.y * 32;
  const int tid = threadIdx.x;
  for (int i = tid; i < 96 * 128; i += 256) {
    int r = i >> 7, c = i & 127;
    int tau = t0 - 63 + r;
    Qw[r][c] = (tau >= 0) ? Q[(b * QROWS + tau) * NC + c] : 0.f;
  }
  for (int i = tid; i < 2048; i += 256) {  // 2048 float4 = 4 scales x 512
    int s = i >> 9, rem = i & 511;
    ((float4*)ps)[i] = ((const float4*)(pi + ((long)s * NT + t0) * NLM))[rem];
  }
  __syncthreads();
  const int c = tid & 127, th = tid >> 7;  // th wave-uniform
  const float pb = phib[c];
  for (int tt = th; tt < 32; tt += 2) {
    const int ti = t0 + tt;
    const float Qt = Qw[tt + 64][c];
    float a0 = 0.f, a1 = 0.f, a2 = 0.f, a3 = 0.f;
#pragma unroll
    for (int l = 0; l < 64; l += 4) {
      float v[4];
#pragma unroll
      for (int u = 0; u < 4; ++u) {
        float sm = (Qt - Qw[tt + 63 - (l + u)][c]) * (1.f / (float)(l + u + 9)) + pb;
        v[u] = tanh_fast(sm);
      }
      float4 w0 = *(const float4*)&ps[0][tt][l];
      float4 w1 = *(const float4*)&ps[1][tt][l];
      float4 w2 = *(const float4*)&ps[2][tt][l];
      float4 w3 = *(const float4*)&ps[3][tt][l];
      a0 = fmaf(w0.x, v[0], a0); a0 = fmaf(w0.y, v[1], a0);
      a0 = fmaf(w0.z, v[2], a0); a0 = fmaf(w0.w, v[3], a0);
      a1 = fmaf(w1.x, v[0], a1); a1 = fmaf(w1.y, v[1], a1);
      a1 = fmaf(w1.z, v[2], a1); a1 = fmaf(w1.w, v[3], a1);
      a2 = fmaf(w2.x, v[0], a2); a2 = fmaf(w2.y, v[1], a2);
      a2 = fmaf(w2.z, v[2], a2); a2 = fmaf(w2.w, v[3], a2);
      a3 = fmaf(w3.x, v[0], a3); a3 = fmaf(w3.y, v[1], a3);
      a3 = fmaf(w3.z, v[2], a3); a3 = fmaf(w3.w, v[3], a3);
    }
    eq[((long)(0 * 8 + b) * NT + ti) * NC + c] = a0;
    eq[((long)(1 * 8 + b) * NT + ti) * NC + c] = a1;
    eq[((long)(2 * 8 + b) * NT + ti) * NC + c] = a2;
    eq[((long)(3 * 8 + b) * NT + ti) * NC + c] = a3;
  }
}

// K5a-basis: per (s,chunk) unit-response CoefT[s][ch][j][t] + local k (e=1).
// pi chunk staged in LDS.
__global__ __launch_bounds__(128) void k5a_basis(const float* __restrict__ pi,
                                                 float* __restrict__ coefT,
                                                 float* __restrict__ klocal) {
  __shared__ __align__(16) float psb[4096];
  const int s = blockIdx.x, ch = blockIdx.y;
  const int tid = threadIdx.x;
  const float* pib = pi + ((long)s * NT + ch * 64) * NLM;
  for (int i = tid; i < 1024; i += 128) ((float4*)psb)[i] = ((const float4*)pib)[i];
  __syncthreads();
  float q[4][16];
  if (tid < 64) {
    const int j = tid;
    tri_scan64([&](int t, int l) { return psb[t * 64 + l]; },
               [&](int t) { int l = t + j; return (l < 64) ? psb[t * 64 + l] : 0.f; }, q);
    float* ct = coefT + (((long)s * NCH + ch) * 64 + j) * 64;
#pragma unroll
    for (int tau = 0; tau < 4; ++tau)
#pragma unroll
      for (int i = 0; i < 16; ++i) ct[tau * 16 + i] = q[tau][i];
  } else if (tid == 64) {
    tri_scan64([&](int t, int l) { return psb[t * 64 + l]; },
               [&](int t) { return 1.f; }, q);
    float* kl = klocal + ((long)s * NCH + ch) * 64;
#pragma unroll
    for (int tau = 0; tau < 4; ++tau)
#pragma unroll
      for (int i = 0; i < 16; ++i) kl[tau * 16 + i] = q[tau][i];
  }
}

// K5a-data: per (s,b,chunk) local scan with zero history, e -> qlocal in place.
__global__ __launch_bounds__(128) void k5a_data(const float* __restrict__ pi,
                                                float* __restrict__ eq) {
  __shared__ __align__(16) float psd[4096];
  const int sb = blockIdx.x;  // s*8+b
  const int s = sb >> 3;
  const int ch = blockIdx.y;
  const int c = threadIdx.x;
  const float* pib = pi + ((long)s * NT + ch * 64) * NLM;
  for (int i = c; i < 1024; i += 128) ((float4*)psd)[i] = ((const float4*)pib)[i];
  __syncthreads();
  float* qb = eq + ((long)sb * NT + ch * 64) * NC + c;
  float q[4][16];
  tri_scan64([&](int t, int l) { return psd[t * 64 + l]; },
             [&](int t) { return qb[t * NC]; }, q);
#pragma unroll
  for (int tau = 0; tau < 4; ++tau)
#pragma unroll
    for (int i = 0; i < 16; ++i) qb[(tau * 16 + i) * NC] = q[tau][i];
}

// K5b merged: blocks 0..63: q cross-chunk combine (sb x 2 channel-halves),
//             blocks 64..67: k cross-chunk combine (per s).
// Coef chunk staged in LDS; next chunk register-prefetched during compute.
__global__ __launch_bounds__(512) void k5b_scan(const float* __restrict__ coefT,
                                                const float* __restrict__ klocal,
                                                float* __restrict__ eq,
                                                float* __restrict__ kout) {
  __shared__ float Hs[64][64];                 // 16 KB (q part)
  __shared__ __align__(16) float cs[64][64];   // 16 KB coef tile
  __shared__ float Hk[64];
  const int tid = threadIdx.x;
  if (blockIdx.x < 64) {
    const int sb = blockIdx.x >> 1, cg = blockIdx.x & 1;
    const int s = sb >> 3;
    const int c = tid & 63;
    const int tq = tid >> 6;  // 0..7, wave-uniform
    for (int i = tid; i < 4096; i += 512) ((float*)Hs)[i] = 0.f;
    const float4* cb = (const float4*)(coefT + (long)s * NCH * 4096);
    {
      float4 c0 = cb[tid], c1 = cb[tid + 512];
      ((float4*)cs)[tid] = c0;
      ((float4*)cs)[tid + 512] = c1;
    }
    __syncthreads();
    for (int ch = 0; ch < NCH; ++ch) {
      float4 n0, n1;
      if (ch + 1 < NCH) {
        n0 = cb[(ch + 1) * 1024 + tid];
        n1 = cb[(ch + 1) * 1024 + tid + 512];
      }
      float* qb = eq + ((long)sb * NT + ch * 64) * NC + cg * 64 + c;
      float ql[8];
#pragma unroll
      for (int i = 0; i < 8; ++i) ql[i] = qb[(tq * 8 + i) * NC];
      float acc[8];
#pragma unroll
      for (int i = 0; i < 8; ++i) acc[i] = 0.f;
#pragma unroll 4
      for (int j = 0; j < 64; ++j) {
        float hj = Hs[j][c];
        const float4* crow = (const float4*)&cs[j][tq * 8];
        float4 w0 = crow[0], w1 = crow[1];
        acc[0] = fmaf(w0.x, hj, acc[0]);
        acc[1] = fmaf(w0.y, hj, acc[1]);
        acc[2] = fmaf(w0.z, hj, acc[2]);
        acc[3] = fmaf(w0.w, hj, acc[3]);
        acc[4] = fmaf(w1.x, hj, acc[4]);
        acc[5] = fmaf(w1.y, hj, acc[5]);
        acc[6] = fmaf(w1.z, hj, acc[6]);
        acc[7] = fmaf(w1.w, hj, acc[7]);
      }
      __syncthreads();
#pragma unroll
      for (int i = 0; i < 8; ++i) {
        const int t = tq * 8 + i;
        float v = acc[i] + ql[i];
        qb[t * NC] = v;
        Hs[63 - t][c] = v;
      }
      if (ch + 1 < NCH) {
        ((float4*)cs)[tid] = n0;
        ((float4*)cs)[tid + 512] = n1;
      }
      __syncthreads();
    }
  } else {
    const int s = blockIdx.x - 64;
    const float4* cb = (const float4*)(coefT + (long)s * NCH * 4096);
    {
      float4 c0 = cb[tid], c1 = cb[tid + 512];
      ((float4*)cs)[tid] = c0;
      ((float4*)cs)[tid + 512] = c1;
    }
    if (tid < 64) Hk[tid] = 0.f;
    __syncthreads();
    for (int ch = 0; ch < NCH; ++ch) {
      float4 n0, n1;
      if (ch + 1 < NCH) {
        n0 = cb[(ch + 1) * 1024 + tid];
        n1 = cb[(ch + 1) * 1024 + tid + 512];
      }
      float acc = 0.f;
      if (tid < 64) {
        acc = klocal[((long)s * NCH + ch) * 64 + tid];
#pragma unroll 8
        for (int j = 0; j < 64; ++j) acc = fmaf(cs[j][tid], Hk[j], acc);
        kout[s * NT + ch * 64 + tid] = acc;
      }
      __syncthreads();
      if (tid < 64) Hk[63 - tid] = acc;
      if (ch + 1 < NCH) {
        ((float4*)cs)[tid] = n0;
        ((float4*)cs)[tid + 512] = n1;
      }
      __syncthreads();
    }
  }
}

// K6: rep = (q + 16*anchor)/(k+16) * (k/(k+16)); out = rep_flat @ mix_w + mix_b
__global__ __launch_bounds__(128) void k6_mix(
    const float* __restrict__ q, const float* __restrict__ kout,
    const float* __restrict__ anchor, const float* __restrict__ mixw,
    const float* __restrict__ mixb, float* __restrict__ out) {
  __shared__ float rsdata[8][512];
  const int b = blockIdx.x;
  const int t0 = blockIdx.y * 8;
  const int tid = threadIdx.x;
  for (int i = tid; i < 8 * 512; i += 128) {
    int r = i >> 9, sc = i & 511;
    int s = sc >> 7, c = sc & 127;
    int ti = t0 + r;
    float qv = q[((long)(s * 8 + b) * NT + ti) * NC + c];
    float kv = kout[s * NT + ti];
    float d1 = 1.f / (kv + 16.f);
    rsdata[r][sc] = (qv + 16.f * anchor[sc]) * d1 * (kv * d1);
  }
  __syncthreads();
  const int co = tid;
  float mb = mixb[co];
  float acc[8];
#pragma unroll
  for (int r = 0; r < 8; ++r) acc[r] = mb;
  for (int kk = 0; kk < 512; ++kk) {
    float w = mixw[kk * 128 + co];
#pragma unroll
    for (int r = 0; r < 8; ++r) acc[r] = fmaf(rsdata[r][kk], w, acc[r]);
  }
#pragma unroll
  for (int r = 0; r < 8; ++r) out[((long)b * NT + t0 + r) * NC + co] = acc[r];
}

extern "C" void kernel_launch(void* const* d_in, const int* in_sizes, int n_in,
                              void* d_out, int out_size, void* d_ws, size_t ws_size,
                              hipStream_t stream) {
  const float* x = (const float*)d_in[0];
  const float* W = (const float*)d_in[1];
  const float* bias = (const float*)d_in[2];
  const float* phiw = (const float*)d_in[3];
  const float* phib = (const float*)d_in[4];
  const float* anchor = (const float*)d_in[5];
  const float* logw = (const float*)d_in[6];
  const float* mixw = (const float*)d_in[7];
  const float* mixb = (const float*)d_in[8];
  float* out = (float*)d_out;

  float* ws = (float*)d_ws;
  float* Q = ws;                                     // 8*2049*128 = 2,098,176
  float* pi = Q + (long)NB * QROWS * NC;             // 4*2048*64  =   524,288
  float* eq = pi + (long)NS * NT * NLM;              // 32*2048*128= 8,388,608
  float* coefT = eq + (long)NS * NB * NT * NC;       // 4*32*64*64 =   524,288
  float* klocal = coefT + (long)NS * NCH * 64 * 64;  //                  8,192
  float* kout = klocal + (long)NS * NCH * 64;        //                  8,192
  float* logZt = kout + (long)NS * NT;               //                  8,196
  float* S2 = logZt + (long)NS * QROWS;              //                 32,768

  hipLaunchKernelGGL(k1_uv, dim3(NB * NT / 8), dim3(128), 0, stream, x, W, bias, phiw, Q);
  hipLaunchKernelGGL(k2a_sums, dim3(NB, NCH), dim3(128), 0, stream, Q, S2);
  hipLaunchKernelGGL(k2b_scan, dim3(NB), dim3(128), 0, stream, S2);
  hipLaunchKernelGGL(k2c_fix, dim3(NB, NCH), dim3(128), 0, stream, Q, S2);
  hipLaunchKernelGGL(k3ab_logz, dim3(NS), dim3(64), 0, stream, logw, logZt);
  hipLaunchKernelGGL(k3c_pi, dim3(NT / 4, NS), dim3(256), 0, stream, logw, logZt, pi);
  hipLaunchKernelGGL(k4_e, dim3(NB, NT / 32), dim3(256), 0, stream, Q, pi, phib, eq);
  hipLaunchKernelGGL(k5a_basis, dim3(NS, NCH), dim3(128), 0, stream, pi, coefT, klocal);
  hipLaunchKernelGGL(k5a_data, dim3(NS * NB, NCH), dim3(128), 0, stream, pi, eq);
  hipLaunchKernelGGL(k5b_scan, dim3(68), dim3(512), 0, stream, coefT, klocal, eq, kout);
  hipLaunchKernelGGL(k6_mix, dim3(NB, NT / 8), dim3(128), 0, stream, eq, kout, anchor, mixw, mixb, out);
}

// Round 4
// 496.692 us; speedup vs baseline: 11.8808x; 1.0790x over previous
//
#include <hip/hip_runtime.h>
#include <math.h>

// Problem constants
#define NB 8
#define NT 2048
#define NC 128
#define NLM 64
#define NS 4
#define QROWS 2049
#define NCH 32  // 2048 / 64 chunks

#define TWO_LOG2E 2.885390081777927f

__device__ __forceinline__ float rcp_fast(float x) {
  return __builtin_amdgcn_rcpf(x);
}

// ---------------------------------------------------------------------------
// Tiled 64-step local linear scan (forward substitution); all indices
// compile-time so q[4][16] stays in VGPRs.
//   q[t] = D(t) + sum_{t'<t} P(t, t-t'-1) * q[t']
// ---------------------------------------------------------------------------
template <typename PF, typename DF>
__device__ __forceinline__ void tri_scan64(PF P, DF D, float q[4][16]) {
#pragma unroll
  for (int tau = 0; tau < 4; ++tau) {
    float acc[16];
#pragma unroll
    for (int i = 0; i < 16; ++i) acc[i] = D(tau * 16 + i);
#pragma unroll
    for (int p = 0; p < 4; ++p) {
      if (p < tau) {
#pragma unroll
        for (int i = 0; i < 16; ++i) {
          const int t = tau * 16 + i;
#pragma unroll
          for (int i2 = 0; i2 < 16; ++i2) {
            acc[i] = fmaf(P(t, t - (p * 16 + i2) - 1), q[p][i2], acc[i]);
          }
        }
      }
    }
#pragma unroll
    for (int i = 0; i < 16; ++i) {
      const int t = tau * 16 + i;
#pragma unroll
      for (int i2 = 0; i2 < 16; ++i2) {
        if (i2 < i) acc[i] = fmaf(P(t, i - i2 - 1), q[tau][i2], acc[i]);
      }
      q[tau][i] = acc[i];
    }
  }
}

// K1: per 8 rows (b,t): z = x@W + b ; u = [cos,sin]/sqrt(dh) ; V = u @ phi_w
__global__ __launch_bounds__(128) void k1_uv(
    const float* __restrict__ x, const float* __restrict__ W,
    const float* __restrict__ bias, const float* __restrict__ phiw,
    float* __restrict__ Q) {
  __shared__ float xs[8][128];
  __shared__ float us[8][256];
  const int j = threadIdx.x;
  const int bt0 = blockIdx.x * 8;
#pragma unroll
  for (int r = 0; r < 8; ++r) xs[r][j] = x[(bt0 + r) * NC + j];
  __syncthreads();
  float z[8];
  const float bj = bias[j];
#pragma unroll
  for (int r = 0; r < 8; ++r) z[r] = bj;
  for (int k = 0; k < 128; ++k) {
    float w = W[k * 128 + j];
#pragma unroll
    for (int r = 0; r < 8; ++r) z[r] = fmaf(xs[r][k], w, z[r]);
  }
  const float rs = 0.08838834764831845f;  // 1/sqrt(128)
#pragma unroll
  for (int r = 0; r < 8; ++r) {
    float sv, cv;
    sincosf(z[r], &sv, &cv);
    us[r][j] = cv * rs;
    us[r][128 + j] = sv * rs;
  }
  __syncthreads();
  float a[8];
#pragma unroll
  for (int r = 0; r < 8; ++r) a[r] = 0.f;
  for (int k = 0; k < 256; ++k) {
    float w = phiw[k * 128 + j];
#pragma unroll
    for (int r = 0; r < 8; ++r) a[r] = fmaf(us[r][k], w, a[r]);
  }
#pragma unroll
  for (int r = 0; r < 8; ++r) {
    int bt = bt0 + r;
    int b = bt >> 11, t = bt & 2047;
    Q[(b * QROWS + t + 1) * NC + j] = a[r];
  }
}

// K2 (chunk-parallel cumsum): a) per-chunk sums, b) per-b scan, c) fixup
__global__ __launch_bounds__(128) void k2a_sums(const float* __restrict__ Q,
                                                float* __restrict__ S2) {
  const int b = blockIdx.x, ch = blockIdx.y, c = threadIdx.x;
  float acc = 0.f;
#pragma unroll 8
  for (int i = 0; i < 64; ++i) acc += Q[(b * QROWS + ch * 64 + 1 + i) * NC + c];
  S2[(b * NCH + ch) * NC + c] = acc;
}

__global__ __launch_bounds__(128) void k2b_scan(float* __restrict__ S2) {
  const int b = blockIdx.x, c = threadIdx.x;
  float acc = 0.f;
  for (int ch = 0; ch < NCH; ++ch) {
    float* p = S2 + (b * NCH + ch) * NC + c;
    float v = *p;
    *p = acc;  // exclusive
    acc += v;
  }
}

__global__ __launch_bounds__(128) void k2c_fix(float* __restrict__ Q,
                                               const float* __restrict__ S2) {
  const int b = blockIdx.x, ch = blockIdx.y, c = threadIdx.x;
  if (ch == 0) Q[(b * QROWS) * NC + c] = 0.f;
  float run = S2[(b * NCH + ch) * NC + c];
#pragma unroll 4
  for (int i = 0; i < 64; ++i) {
    float* p = Q + (b * QROWS + ch * 64 + 1 + i) * NC + c;
    run += *p;
    *p = run;
  }
}

// K3ab fused: unit-response matrix mT of the Z recurrence (LDS) + 32
// sequential chunk-steps of the rescaled linear logZ evolution. Per s.
__global__ __launch_bounds__(64) void k3ab_logz(const float* __restrict__ logw,
                                                float* __restrict__ logZt) {
  const int s = blockIdx.x;
  const int j = threadIdx.x;  // doubles as t in phase 2
  __shared__ float wx[64];
  __shared__ float mTs[64][65];  // [j][t], padded (writes are row-per-lane)
  __shared__ float Zr[64];
  wx[j] = __expf(logw[s * NLM + j]);
  __syncthreads();
  float q[4][16];
  tri_scan64([&](int t, int l) { return wx[l]; },
             [&](int t) { int l = t + j; return (l < 64) ? wx[l] : 0.f; }, q);
#pragma unroll
  for (int tau = 0; tau < 4; ++tau)
#pragma unroll
    for (int i = 0; i < 16; ++i) mTs[j][tau * 16 + i] = q[tau][i];
  // phase 2
  const int t = j;
  Zr[t] = (t == 0) ? 1.f : 0.f;
  if (t == 0) logZt[s * QROWS] = 0.f;
  float off = 0.f;
  __syncthreads();
  for (int ch = 0; ch < NCH; ++ch) {
    float acc = 0.f;
#pragma unroll 8
    for (int jj = 0; jj < 64; ++jj) acc = fmaf(mTs[jj][t], Zr[jj], acc);
    logZt[s * QROWS + ch * 64 + 1 + t] = logf(acc) + off;
    float mx = acc;
#pragma unroll
    for (int o = 32; o; o >>= 1) mx = fmaxf(mx, __shfl_xor(mx, o));
    __syncthreads();
    Zr[63 - t] = acc / mx;
    off += logf(mx);
    __syncthreads();
  }
}

// K3c: pi[s][ti][l] = softmax_l(lw[l] + logZ[ti-l]) — fully parallel.
__global__ __launch_bounds__(256) void k3c_pi(const float* __restrict__ logw,
                                              const float* __restrict__ logZt,
                                              float* __restrict__ pi) {
  const int s = blockIdx.y;
  const int ti = blockIdx.x * 4 + (threadIdx.x >> 6);
  const int l = threadIdx.x & 63;
  float la = -INFINITY;
  if (ti - l >= 0) la = logw[s * NLM + l] + logZt[s * QROWS + ti - l];
  float m = la;
#pragma unroll
  for (int o = 32; o; o >>= 1) m = fmaxf(m, __shfl_xor(m, o));
  float p = __expf(la - m);
  float zs = p;
#pragma unroll
  for (int o = 32; o; o >>= 1) zs += __shfl_xor(zs, o);
  pi[((long)s * NT + ti) * NLM + l] = p * rcp_fast(zs);
}

// K4: e[s,b,ti,c] = 1 - 2 * sum_l pi[s,ti,l] * rcp(exp2(y)+1),
//     y = (Q[ti+1]-Q[ti-l]) * (2log2e/(l+9)) + 2log2e*phi_b
// (uses sum_l pi = 1 to fold the tanh affine into one final fma).
// Channel-split blocks: LDS 24+32=56 KB -> 2 blocks/CU (R3 was 80 KB -> 1).
__global__ __launch_bounds__(256) void k4_e(
    const float* __restrict__ Q, const float* __restrict__ pi,
    const float* __restrict__ phib, float* __restrict__ eq) {
  __shared__ float Qw[96][64];                   // 24 KB
  __shared__ __align__(16) float ps[4][32][64];  // 32 KB
  const int b = blockIdx.x;
  const int t0 = blockIdx.y * 32;
  const int half = blockIdx.z;
  const int tid = threadIdx.x;
  for (int i = tid; i < 96 * 64; i += 256) {
    int r = i >> 6, cc = i & 63;
    int tau = t0 - 63 + r;
    Qw[r][cc] = (tau >= 0) ? Q[(b * QROWS + tau) * NC + half * 64 + cc] : 0.f;
  }
  for (int i = tid; i < 2048; i += 256) {  // 2048 float4 = 4 scales x 512
    int s = i >> 9, rem = i & 511;
    ((float4*)ps)[i] = ((const float4*)(pi + ((long)s * NT + t0) * NLM))[rem];
  }
  __syncthreads();
  const int c = tid & 63, tg = tid >> 6;  // tg wave-uniform
  const float pb2 = phib[half * 64 + c] * TWO_LOG2E;
  for (int tt = tg; tt < 32; tt += 4) {
    const int ti = t0 + tt;
    const float Qt = Qw[tt + 64][c];
    float a0 = 0.f, a1 = 0.f, a2 = 0.f, a3 = 0.f;
#pragma unroll
    for (int l = 0; l < 64; l += 4) {
      float v[4];
#pragma unroll
      for (int u = 0; u < 4; ++u) {
        const float cl = TWO_LOG2E / (float)(l + u + 9);  // folded constant
        float y = (Qt - Qw[tt + 63 - (l + u)][c]) * cl + pb2;
        v[u] = rcp_fast(__builtin_exp2f(y) + 1.f);
      }
      float4 w0 = *(const float4*)&ps[0][tt][l];
      float4 w1 = *(const float4*)&ps[1][tt][l];
      float4 w2 = *(const float4*)&ps[2][tt][l];
      float4 w3 = *(const float4*)&ps[3][tt][l];
      a0 = fmaf(w0.x, v[0], a0); a0 = fmaf(w0.y, v[1], a0);
      a0 = fmaf(w0.z, v[2], a0); a0 = fmaf(w0.w, v[3], a0);
      a1 = fmaf(w1.x, v[0], a1); a1 = fmaf(w1.y, v[1], a1);
      a1 = fmaf(w1.z, v[2], a1); a1 = fmaf(w1.w, v[3], a1);
      a2 = fmaf(w2.x, v[0], a2); a2 = fmaf(w2.y, v[1], a2);
      a2 = fmaf(w2.z, v[2], a2); a2 = fmaf(w2.w, v[3], a2);
      a3 = fmaf(w3.x, v[0], a3); a3 = fmaf(w3.y, v[1], a3);
      a3 = fmaf(w3.z, v[2], a3); a3 = fmaf(w3.w, v[3], a3);
    }
    const long base = half * 64 + c;
    eq[((long)(0 * 8 + b) * NT + ti) * NC + base] = fmaf(-2.f, a0, 1.f);
    eq[((long)(1 * 8 + b) * NT + ti) * NC + base] = fmaf(-2.f, a1, 1.f);
    eq[((long)(2 * 8 + b) * NT + ti) * NC + base] = fmaf(-2.f, a2, 1.f);
    eq[((long)(3 * 8 + b) * NT + ti) * NC + base] = fmaf(-2.f, a3, 1.f);
  }
}

// K5a merged: blocks x<32: per (s,b,chunk) local data scan (e -> qlocal);
//             blocks x>=32: per (s,chunk) unit-response CoefT + local k.
__global__ __launch_bounds__(128) void k5a_local(const float* __restrict__ pi,
                                                 float* __restrict__ eq,
                                                 float* __restrict__ coefT,
                                                 float* __restrict__ klocal) {
  __shared__ __align__(16) float psd[4096];
  const int ch = blockIdx.y;
  const int tid = threadIdx.x;
  if (blockIdx.x < 32) {
    const int sb = blockIdx.x;  // s*8+b
    const int s = sb >> 3;
    const int c = tid;
    const float* pib = pi + ((long)s * NT + ch * 64) * NLM;
    for (int i = c; i < 1024; i += 128) ((float4*)psd)[i] = ((const float4*)pib)[i];
    __syncthreads();
    float* qb = eq + ((long)sb * NT + ch * 64) * NC + c;
    float q[4][16];
    tri_scan64([&](int t, int l) { return psd[t * 64 + l]; },
               [&](int t) { return qb[t * NC]; }, q);
#pragma unroll
    for (int tau = 0; tau < 4; ++tau)
#pragma unroll
      for (int i = 0; i < 16; ++i) qb[(tau * 16 + i) * NC] = q[tau][i];
  } else {
    const int s = blockIdx.x - 32;
    const float* pib = pi + ((long)s * NT + ch * 64) * NLM;
    for (int i = tid; i < 1024; i += 128) ((float4*)psd)[i] = ((const float4*)pib)[i];
    __syncthreads();
    float q[4][16];
    if (tid < 64) {
      const int j = tid;
      tri_scan64([&](int t, int l) { return psd[t * 64 + l]; },
                 [&](int t) { int l = t + j; return (l < 64) ? psd[t * 64 + l] : 0.f; }, q);
      float* ct = coefT + (((long)s * NCH + ch) * 64 + j) * 64;
#pragma unroll
      for (int tau = 0; tau < 4; ++tau)
#pragma unroll
        for (int i = 0; i < 16; ++i) ct[tau * 16 + i] = q[tau][i];
    } else if (tid == 64) {
      tri_scan64([&](int t, int l) { return psd[t * 64 + l]; },
                 [&](int t) { return 1.f; }, q);
      float* kl = klocal + ((long)s * NCH + ch) * 64;
#pragma unroll
      for (int tau = 0; tau < 4; ++tau)
#pragma unroll
        for (int i = 0; i < 16; ++i) kl[tau * 16 + i] = q[tau][i];
    }
  }
}

// K5b merged: blocks 0..63: q cross-chunk combine (sb x 2 channel-halves),
//             blocks 64..67: k cross-chunk combine (per s).
// Coef chunk staged in LDS; next chunk register-prefetched during compute.
__global__ __launch_bounds__(512) void k5b_scan(const float* __restrict__ coefT,
                                                const float* __restrict__ klocal,
                                                float* __restrict__ eq,
                                                float* __restrict__ kout) {
  __shared__ float Hs[64][64];                 // 16 KB (q part)
  __shared__ __align__(16) float cs[64][64];   // 16 KB coef tile
  __shared__ float Hk[64];
  const int tid = threadIdx.x;
  if (blockIdx.x < 64) {
    const int sb = blockIdx.x >> 1, cg = blockIdx.x & 1;
    const int s = sb >> 3;
    const int c = tid & 63;
    const int tq = tid >> 6;  // 0..7, wave-uniform
    for (int i = tid; i < 4096; i += 512) ((float*)Hs)[i] = 0.f;
    const float4* cb = (const float4*)(coefT + (long)s * NCH * 4096);
    {
      float4 c0 = cb[tid], c1 = cb[tid + 512];
      ((float4*)cs)[tid] = c0;
      ((float4*)cs)[tid + 512] = c1;
    }
    __syncthreads();
    for (int ch = 0; ch < NCH; ++ch) {
      float4 n0, n1;
      if (ch + 1 < NCH) {
        n0 = cb[(ch + 1) * 1024 + tid];
        n1 = cb[(ch + 1) * 1024 + tid + 512];
      }
      float* qb = eq + ((long)sb * NT + ch * 64) * NC + cg * 64 + c;
      float ql[8];
#pragma unroll
      for (int i = 0; i < 8; ++i) ql[i] = qb[(tq * 8 + i) * NC];
      float acc[8];
#pragma unroll
      for (int i = 0; i < 8; ++i) acc[i] = 0.f;
#pragma unroll 4
      for (int j = 0; j < 64; ++j) {
        float hj = Hs[j][c];
        const float4* crow = (const float4*)&cs[j][tq * 8];
        float4 w0 = crow[0], w1 = crow[1];
        acc[0] = fmaf(w0.x, hj, acc[0]);
        acc[1] = fmaf(w0.y, hj, acc[1]);
        acc[2] = fmaf(w0.z, hj, acc[2]);
        acc[3] = fmaf(w0.w, hj, acc[3]);
        acc[4] = fmaf(w1.x, hj, acc[4]);
        acc[5] = fmaf(w1.y, hj, acc[5]);
        acc[6] = fmaf(w1.z, hj, acc[6]);
        acc[7] = fmaf(w1.w, hj, acc[7]);
      }
      __syncthreads();
#pragma unroll
      for (int i = 0; i < 8; ++i) {
        const int t = tq * 8 + i;
        float v = acc[i] + ql[i];
        qb[t * NC] = v;
        Hs[63 - t][c] = v;
      }
      if (ch + 1 < NCH) {
        ((float4*)cs)[tid] = n0;
        ((float4*)cs)[tid + 512] = n1;
      }
      __syncthreads();
    }
  } else {
    const int s = blockIdx.x - 64;
    const float4* cb = (const float4*)(coefT + (long)s * NCH * 4096);
    {
      float4 c0 = cb[tid], c1 = cb[tid + 512];
      ((float4*)cs)[tid] = c0;
      ((float4*)cs)[tid + 512] = c1;
    }
    if (tid < 64) Hk[tid] = 0.f;
    __syncthreads();
    for (int ch = 0; ch < NCH; ++ch) {
      float4 n0, n1;
      if (ch + 1 < NCH) {
        n0 = cb[(ch + 1) * 1024 + tid];
        n1 = cb[(ch + 1) * 1024 + tid + 512];
      }
      float acc = 0.f;
      if (tid < 64) {
        acc = klocal[((long)s * NCH + ch) * 64 + tid];
#pragma unroll 8
        for (int j = 0; j < 64; ++j) acc = fmaf(cs[j][tid], Hk[j], acc);
        kout[s * NT + ch * 64 + tid] = acc;
      }
      __syncthreads();
      if (tid < 64) Hk[63 - tid] = acc;
      if (ch + 1 < NCH) {
        ((float4*)cs)[tid] = n0;
        ((float4*)cs)[tid + 512] = n1;
      }
      __syncthreads();
    }
  }
}

// K6: rep = (q + 16*anchor)/(k+16) * (k/(k+16)); out = rep_flat @ mix_w + mix_b
__global__ __launch_bounds__(128) void k6_mix(
    const float* __restrict__ q, const float* __restrict__ kout,
    const float* __restrict__ anchor, const float* __restrict__ mixw,
    const float* __restrict__ mixb, float* __restrict__ out) {
  __shared__ float rsdata[8][512];
  const int b = blockIdx.x;
  const int t0 = blockIdx.y * 8;
  const int tid = threadIdx.x;
  for (int i = tid; i < 8 * 512; i += 128) {
    int r = i >> 9, sc = i & 511;
    int s = sc >> 7, c = sc & 127;
    int ti = t0 + r;
    float qv = q[((long)(s * 8 + b) * NT + ti) * NC + c];
    float kv = kout[s * NT + ti];
    float d1 = rcp_fast(kv + 16.f);
    rsdata[r][sc] = (qv + 16.f * anchor[sc]) * d1 * (kv * d1);
  }
  __syncthreads();
  const int co = tid;
  float mb = mixb[co];
  float acc[8];
#pragma unroll
  for (int r = 0; r < 8; ++r) acc[r] = mb;
  for (int kk = 0; kk < 512; ++kk) {
    float w = mixw[kk * 128 + co];
#pragma unroll
    for (int r = 0; r < 8; ++r) acc[r] = fmaf(rsdata[r][kk], w, acc[r]);
  }
#pragma unroll
  for (int r = 0; r < 8; ++r) out[((long)b * NT + t0 + r) * NC + co] = acc[r];
}

extern "C" void kernel_launch(void* const* d_in, const int* in_sizes, int n_in,
                              void* d_out, int out_size, void* d_ws, size_t ws_size,
                              hipStream_t stream) {
  const float* x = (const float*)d_in[0];
  const float* W = (const float*)d_in[1];
  const float* bias = (const float*)d_in[2];
  const float* phiw = (const float*)d_in[3];
  const float* phib = (const float*)d_in[4];
  const float* anchor = (const float*)d_in[5];
  const float* logw = (const float*)d_in[6];
  const float* mixw = (const float*)d_in[7];
  const float* mixb = (const float*)d_in[8];
  float* out = (float*)d_out;

  float* ws = (float*)d_ws;
  float* Q = ws;                                     // 8*2049*128 = 2,098,176
  float* pi = Q + (long)NB * QROWS * NC;             // 4*2048*64  =   524,288
  float* eq = pi + (long)NS * NT * NLM;              // 32*2048*128= 8,388,608
  float* coefT = eq + (long)NS * NB * NT * NC;       // 4*32*64*64 =   524,288
  float* klocal = coefT + (long)NS * NCH * 64 * 64;  //                  8,192
  float* kout = klocal + (long)NS * NCH * 64;        //                  8,192
  float* logZt = kout + (long)NS * NT;               //                  8,196
  float* S2 = logZt + (long)NS * QROWS;              //                 32,768

  hipLaunchKernelGGL(k1_uv, dim3(NB * NT / 8), dim3(128), 0, stream, x, W, bias, phiw, Q);
  hipLaunchKernelGGL(k2a_sums, dim3(NB, NCH), dim3(128), 0, stream, Q, S2);
  hipLaunchKernelGGL(k2b_scan, dim3(NB), dim3(128), 0, stream, S2);
  hipLaunchKernelGGL(k2c_fix, dim3(NB, NCH), dim3(128), 0, stream, Q, S2);
  hipLaunchKernelGGL(k3ab_logz, dim3(NS), dim3(64), 0, stream, logw, logZt);
  hipLaunchKernelGGL(k3c_pi, dim3(NT / 4, NS), dim3(256), 0, stream, logw, logZt, pi);
  hipLaunchKernelGGL(k4_e, dim3(NB, NT / 32, 2), dim3(256), 0, stream, Q, pi, phib, eq);
  hipLaunchKernelGGL(k5a_local, dim3(NS * NB + NS, NCH), dim3(128), 0, stream, pi, eq, coefT, klocal);
  hipLaunchKernelGGL(k5b_scan, dim3(68), dim3(512), 0, stream, coefT, klocal, eq, kout);
  hipLaunchKernelGGL(k6_mix, dim3(NB, NT / 8), dim3(128), 0, stream, eq, kout, anchor, mixw, mixb, out);
}

// Round 5
// 490.869 us; speedup vs baseline: 12.0218x; 1.0119x over previous
//
#include <hip/hip_runtime.h>
#include <math.h>

// Problem constants
#define NB 8
#define NT 2048
#define NC 128
#define NLM 64
#define NS 4
#define QROWS 2049
#define NCH 32  // 2048 / 64 chunks

#define TWO_LOG2E 2.885390081777927f

__device__ __forceinline__ float rcp_fast(float x) {
  return __builtin_amdgcn_rcpf(x);
}

// ---------------------------------------------------------------------------
// Tiled 64-step local linear scan (forward substitution); all indices
// compile-time so q[4][16] stays in VGPRs.
//   q[t] = D(t) + sum_{t'<t} P(t, t-t'-1) * q[t']
// ---------------------------------------------------------------------------
template <typename PF, typename DF>
__device__ __forceinline__ void tri_scan64(PF P, DF D, float q[4][16]) {
#pragma unroll
  for (int tau = 0; tau < 4; ++tau) {
    float acc[16];
#pragma unroll
    for (int i = 0; i < 16; ++i) acc[i] = D(tau * 16 + i);
#pragma unroll
    for (int p = 0; p < 4; ++p) {
      if (p < tau) {
#pragma unroll
        for (int i = 0; i < 16; ++i) {
          const int t = tau * 16 + i;
#pragma unroll
          for (int i2 = 0; i2 < 16; ++i2) {
            acc[i] = fmaf(P(t, t - (p * 16 + i2) - 1), q[p][i2], acc[i]);
          }
        }
      }
    }
#pragma unroll
    for (int i = 0; i < 16; ++i) {
      const int t = tau * 16 + i;
#pragma unroll
      for (int i2 = 0; i2 < 16; ++i2) {
        if (i2 < i) acc[i] = fmaf(P(t, i - i2 - 1), q[tau][i2], acc[i]);
      }
      q[tau][i] = acc[i];
    }
  }
}

// K1: per 8 rows (b,t): z = x@W + b ; u = [cos,sin]/sqrt(dh) ; V = u @ phi_w
__global__ __launch_bounds__(128) void k1_uv(
    const float* __restrict__ x, const float* __restrict__ W,
    const float* __restrict__ bias, const float* __restrict__ phiw,
    float* __restrict__ Q) {
  __shared__ float xs[8][128];
  __shared__ float us[8][256];
  const int j = threadIdx.x;
  const int bt0 = blockIdx.x * 8;
#pragma unroll
  for (int r = 0; r < 8; ++r) xs[r][j] = x[(bt0 + r) * NC + j];
  __syncthreads();
  float z[8];
  const float bj = bias[j];
#pragma unroll
  for (int r = 0; r < 8; ++r) z[r] = bj;
  for (int k = 0; k < 128; ++k) {
    float w = W[k * 128 + j];
#pragma unroll
    for (int r = 0; r < 8; ++r) z[r] = fmaf(xs[r][k], w, z[r]);
  }
  const float rs = 0.08838834764831845f;  // 1/sqrt(128)
#pragma unroll
  for (int r = 0; r < 8; ++r) {
    float sv, cv;
    sincosf(z[r], &sv, &cv);
    us[r][j] = cv * rs;
    us[r][128 + j] = sv * rs;
  }
  __syncthreads();
  float a[8];
#pragma unroll
  for (int r = 0; r < 8; ++r) a[r] = 0.f;
  for (int k = 0; k < 256; ++k) {
    float w = phiw[k * 128 + j];
#pragma unroll
    for (int r = 0; r < 8; ++r) a[r] = fmaf(us[r][k], w, a[r]);
  }
#pragma unroll
  for (int r = 0; r < 8; ++r) {
    int bt = bt0 + r;
    int b = bt >> 11, t = bt & 2047;
    Q[(b * QROWS + t + 1) * NC + j] = a[r];
  }
}

// K2 (chunk-parallel cumsum): a) per-chunk sums, b) per-b scan, c) fixup
__global__ __launch_bounds__(128) void k2a_sums(const float* __restrict__ Q,
                                                float* __restrict__ S2) {
  const int b = blockIdx.x, ch = blockIdx.y, c = threadIdx.x;
  float acc = 0.f;
#pragma unroll 8
  for (int i = 0; i < 64; ++i) acc += Q[(b * QROWS + ch * 64 + 1 + i) * NC + c];
  S2[(b * NCH + ch) * NC + c] = acc;
}

__global__ __launch_bounds__(128) void k2b_scan(float* __restrict__ S2) {
  const int b = blockIdx.x, c = threadIdx.x;
  float acc = 0.f;
  for (int ch = 0; ch < NCH; ++ch) {
    float* p = S2 + (b * NCH + ch) * NC + c;
    float v = *p;
    *p = acc;  // exclusive
    acc += v;
  }
}

__global__ __launch_bounds__(128) void k2c_fix(float* __restrict__ Q,
                                               const float* __restrict__ S2) {
  const int b = blockIdx.x, ch = blockIdx.y, c = threadIdx.x;
  if (ch == 0) Q[(b * QROWS) * NC + c] = 0.f;
  float run = S2[(b * NCH + ch) * NC + c];
#pragma unroll 4
  for (int i = 0; i < 64; ++i) {
    float* p = Q + (b * QROWS + ch * 64 + 1 + i) * NC + c;
    run += *p;
    *p = run;
  }
}

// K3ab fused: unit-response matrix mT of the Z recurrence (LDS) + 32
// sequential chunk-steps of the rescaled linear logZ evolution. Per s.
__global__ __launch_bounds__(64) void k3ab_logz(const float* __restrict__ logw,
                                                float* __restrict__ logZt) {
  const int s = blockIdx.x;
  const int j = threadIdx.x;  // doubles as t in phase 2
  __shared__ float wx[64];
  __shared__ float mTs[64][65];  // [j][t], padded (writes are row-per-lane)
  __shared__ float Zr[64];
  wx[j] = __expf(logw[s * NLM + j]);
  __syncthreads();
  float q[4][16];
  tri_scan64([&](int t, int l) { return wx[l]; },
             [&](int t) { int l = t + j; return (l < 64) ? wx[l] : 0.f; }, q);
#pragma unroll
  for (int tau = 0; tau < 4; ++tau)
#pragma unroll
    for (int i = 0; i < 16; ++i) mTs[j][tau * 16 + i] = q[tau][i];
  // phase 2
  const int t = j;
  Zr[t] = (t == 0) ? 1.f : 0.f;
  if (t == 0) logZt[s * QROWS] = 0.f;
  float off = 0.f;
  __syncthreads();
  for (int ch = 0; ch < NCH; ++ch) {
    float acc = 0.f;
#pragma unroll 8
    for (int jj = 0; jj < 64; ++jj) acc = fmaf(mTs[jj][t], Zr[jj], acc);
    logZt[s * QROWS + ch * 64 + 1 + t] = logf(acc) + off;
    float mx = acc;
#pragma unroll
    for (int o = 32; o; o >>= 1) mx = fmaxf(mx, __shfl_xor(mx, o));
    __syncthreads();
    Zr[63 - t] = acc / mx;
    off += logf(mx);
    __syncthreads();
  }
}

// K3c: pi[s][ti][l] = softmax_l(lw[l] + logZ[ti-l]) — fully parallel.
__global__ __launch_bounds__(256) void k3c_pi(const float* __restrict__ logw,
                                              const float* __restrict__ logZt,
                                              float* __restrict__ pi) {
  const int s = blockIdx.y;
  const int ti = blockIdx.x * 4 + (threadIdx.x >> 6);
  const int l = threadIdx.x & 63;
  float la = -INFINITY;
  if (ti - l >= 0) la = logw[s * NLM + l] + logZt[s * QROWS + ti - l];
  float m = la;
#pragma unroll
  for (int o = 32; o; o >>= 1) m = fmaxf(m, __shfl_xor(m, o));
  float p = __expf(la - m);
  float zs = p;
#pragma unroll
  for (int o = 32; o; o >>= 1) zs += __shfl_xor(zs, o);
  pi[((long)s * NT + ti) * NLM + l] = p * rcp_fast(zs);
}

// K4: e[s,b,ti,c] = 1 - 2 * sum_l pi[s,ti,l] * rcp(exp2(y)+1)
__global__ __launch_bounds__(256) void k4_e(
    const float* __restrict__ Q, const float* __restrict__ pi,
    const float* __restrict__ phib, float* __restrict__ eq) {
  __shared__ float Qw[96][64];                   // 24 KB
  __shared__ __align__(16) float ps[4][32][64];  // 32 KB
  const int b = blockIdx.x;
  const int t0 = blockIdx.y * 32;
  const int half = blockIdx.z;
  const int tid = threadIdx.x;
  for (int i = tid; i < 96 * 64; i += 256) {
    int r = i >> 6, cc = i & 63;
    int tau = t0 - 63 + r;
    Qw[r][cc] = (tau >= 0) ? Q[(b * QROWS + tau) * NC + half * 64 + cc] : 0.f;
  }
  for (int i = tid; i < 2048; i += 256) {  // 2048 float4 = 4 scales x 512
    int s = i >> 9, rem = i & 511;
    ((float4*)ps)[i] = ((const float4*)(pi + ((long)s * NT + t0) * NLM))[rem];
  }
  __syncthreads();
  const int c = tid & 63, tg = tid >> 6;  // tg wave-uniform
  const float pb2 = phib[half * 64 + c] * TWO_LOG2E;
  for (int tt = tg; tt < 32; tt += 4) {
    const int ti = t0 + tt;
    const float Qt = Qw[tt + 64][c];
    float a0 = 0.f, a1 = 0.f, a2 = 0.f, a3 = 0.f;
#pragma unroll
    for (int l = 0; l < 64; l += 4) {
      float v[4];
#pragma unroll
      for (int u = 0; u < 4; ++u) {
        const float cl = TWO_LOG2E / (float)(l + u + 9);  // folded constant
        float y = (Qt - Qw[tt + 63 - (l + u)][c]) * cl + pb2;
        v[u] = rcp_fast(__builtin_exp2f(y) + 1.f);
      }
      float4 w0 = *(const float4*)&ps[0][tt][l];
      float4 w1 = *(const float4*)&ps[1][tt][l];
      float4 w2 = *(const float4*)&ps[2][tt][l];
      float4 w3 = *(const float4*)&ps[3][tt][l];
      a0 = fmaf(w0.x, v[0], a0); a0 = fmaf(w0.y, v[1], a0);
      a0 = fmaf(w0.z, v[2], a0); a0 = fmaf(w0.w, v[3], a0);
      a1 = fmaf(w1.x, v[0], a1); a1 = fmaf(w1.y, v[1], a1);
      a1 = fmaf(w1.z, v[2], a1); a1 = fmaf(w1.w, v[3], a1);
      a2 = fmaf(w2.x, v[0], a2); a2 = fmaf(w2.y, v[1], a2);
      a2 = fmaf(w2.z, v[2], a2); a2 = fmaf(w2.w, v[3], a2);
      a3 = fmaf(w3.x, v[0], a3); a3 = fmaf(w3.y, v[1], a3);
      a3 = fmaf(w3.z, v[2], a3); a3 = fmaf(w3.w, v[3], a3);
    }
    const long base = half * 64 + c;
    eq[((long)(0 * 8 + b) * NT + ti) * NC + base] = fmaf(-2.f, a0, 1.f);
    eq[((long)(1 * 8 + b) * NT + ti) * NC + base] = fmaf(-2.f, a1, 1.f);
    eq[((long)(2 * 8 + b) * NT + ti) * NC + base] = fmaf(-2.f, a2, 1.f);
    eq[((long)(3 * 8 + b) * NT + ti) * NC + base] = fmaf(-2.f, a3, 1.f);
  }
}

// K5a-basis (per s,ch): threads 0..63 compute impulse-response columns
// R[:,t'] (R = (I-L)^-1); threads 64..127 compute history responses coefT
// (both layouts); klocal = row sums of R.
__global__ __launch_bounds__(128) void k5a_basis(const float* __restrict__ pi,
                                                 float* __restrict__ rt,
                                                 float* __restrict__ ct,
                                                 float* __restrict__ ctT,
                                                 float* __restrict__ klocal) {
  __shared__ __align__(16) float psd[4096];
  __shared__ float Rl[64][65];
  const int s = blockIdx.x, ch = blockIdx.y;
  const int tid = threadIdx.x;
  const float* pib = pi + ((long)s * NT + ch * 64) * NLM;
  for (int i = tid; i < 1024; i += 128) ((float4*)psd)[i] = ((const float4*)pib)[i];
  __syncthreads();
  float q[4][16];
  if (tid < 64) {
    const int tp = tid;  // impulse position
    tri_scan64([&](int t, int l) { return psd[t * 64 + l]; },
               [&](int t) { return (t == tp) ? 1.f : 0.f; }, q);
    float* rrow = rt + (((long)s * NCH + ch) * 64 + tp) * 64;  // RT[t'][t]
#pragma unroll
    for (int tau = 0; tau < 4; ++tau)
#pragma unroll
      for (int i = 0; i < 16; ++i) {
        rrow[tau * 16 + i] = q[tau][i];
        Rl[tp][tau * 16 + i] = q[tau][i];
      }
  } else {
    const int j = tid - 64;  // history lookback j+1
    tri_scan64([&](int t, int l) { return psd[t * 64 + l]; },
               [&](int t) { int l = t + j; return (l < 64) ? psd[t * 64 + l] : 0.f; }, q);
    float* crow = ct + (((long)s * NCH + ch) * 64 + j) * 64;  // [j][t]
    float* ctb = ctT + ((long)s * NCH + ch) * 4096;           // [t][j]
#pragma unroll
    for (int tau = 0; tau < 4; ++tau)
#pragma unroll
      for (int i = 0; i < 16; ++i) {
        crow[tau * 16 + i] = q[tau][i];
        ctb[(tau * 16 + i) * 64 + j] = q[tau][i];
      }
  }
  __syncthreads();
  if (tid < 64) {  // klocal[t] = sum_t' R[t][t']
    float acc = 0.f;
#pragma unroll 8
    for (int tp = 0; tp < 64; ++tp) acc += Rl[tp][tid];
    klocal[((long)s * NCH + ch) * 64 + tid] = acc;
  }
}

// K5a-data: qlocal = R @ e per (s,b,chunk) — pure GEMM, no serial chain.
__global__ __launch_bounds__(512) void k5a_data(const float* __restrict__ rt,
                                                float* __restrict__ eq) {
  __shared__ float rts[64][64];                // [t'][t] 16 KB
  __shared__ __align__(16) float es[64][128];  // 32 KB
  const int sb = blockIdx.x;  // s*8+b
  const int s = sb >> 3;
  const int ch = blockIdx.y;
  const int tid = threadIdx.x;
  const float4* rsrc = (const float4*)(rt + ((long)s * NCH + ch) * 4096);
  ((float4*)rts)[tid] = rsrc[tid];
  ((float4*)rts)[tid + 512] = rsrc[tid + 512];
  float* qb = eq + ((long)sb * NT + ch * 64) * NC;
  {
    const float4* esrc = (const float4*)qb;
    ((float4*)es)[tid] = esrc[tid];
    ((float4*)es)[tid + 512] = esrc[tid + 512];
    ((float4*)es)[tid + 1024] = esrc[tid + 1024];
    ((float4*)es)[tid + 1536] = esrc[tid + 1536];
  }
  __syncthreads();
  const int t = tid & 63, cw = tid >> 6;  // cw: 16-channel group (wave-uniform)
  float acc[16];
#pragma unroll
  for (int i = 0; i < 16; ++i) acc[i] = 0.f;
#pragma unroll 8
  for (int tp = 0; tp < 64; ++tp) {
    float rv = rts[tp][t];
    const float4* ev = (const float4*)&es[tp][cw * 16];
    float4 e0 = ev[0], e1 = ev[1], e2 = ev[2], e3 = ev[3];
    acc[0] = fmaf(rv, e0.x, acc[0]);  acc[1] = fmaf(rv, e0.y, acc[1]);
    acc[2] = fmaf(rv, e0.z, acc[2]);  acc[3] = fmaf(rv, e0.w, acc[3]);
    acc[4] = fmaf(rv, e1.x, acc[4]);  acc[5] = fmaf(rv, e1.y, acc[5]);
    acc[6] = fmaf(rv, e1.z, acc[6]);  acc[7] = fmaf(rv, e1.w, acc[7]);
    acc[8] = fmaf(rv, e2.x, acc[8]);  acc[9] = fmaf(rv, e2.y, acc[9]);
    acc[10] = fmaf(rv, e2.z, acc[10]); acc[11] = fmaf(rv, e2.w, acc[11]);
    acc[12] = fmaf(rv, e3.x, acc[12]); acc[13] = fmaf(rv, e3.y, acc[13]);
    acc[14] = fmaf(rv, e3.z, acc[14]); acc[15] = fmaf(rv, e3.w, acc[15]);
  }
  float4* dst = (float4*)(qb + t * NC + cw * 16);
  dst[0] = make_float4(acc[0], acc[1], acc[2], acc[3]);
  dst[1] = make_float4(acc[4], acc[5], acc[6], acc[7]);
  dst[2] = make_float4(acc[8], acc[9], acc[10], acc[11]);
  dst[3] = make_float4(acc[12], acc[13], acc[14], acc[15]);
}

// K5b: blocks 0..127: q cross-chunk combine (sb x 4 channel-quarters),
//      coef rows in VGPRs (from ctT), only H in LDS.
//      blocks 128..131: k cross-chunk combine (per s).
__global__ __launch_bounds__(256) void k5b_scan(const float* __restrict__ ctT,
                                                const float* __restrict__ ct,
                                                const float* __restrict__ klocal,
                                                float* __restrict__ eq,
                                                float* __restrict__ kout) {
  const int tid = threadIdx.x;
  if (blockIdx.x < 128) {
    __shared__ __align__(16) float Hq[64][36];  // pad 36: 16B-aligned rows
    const int sb = blockIdx.x >> 2, qd = blockIdx.x & 3;
    const int s = sb >> 3;
    const int t = tid & 63, cw = tid >> 6;  // 4 waves, 8 channels each
    const int c0 = qd * 32 + cw * 8;
    for (int i = tid; i < 64 * 36; i += 256) ((float*)Hq)[i] = 0.f;
    __syncthreads();
    const float* ctTs = ctT + (long)s * NCH * 4096;
    for (int ch = 0; ch < NCH; ++ch) {
      float cr[64];
      {
        const float4* cro = (const float4*)(ctTs + ((long)ch * 64 + t) * 64);
        float4* crv = (float4*)cr;
#pragma unroll
        for (int i = 0; i < 16; ++i) crv[i] = cro[i];
      }
      float* qp = eq + ((long)sb * NT + ch * 64 + t) * NC + c0;
      float4 ql0 = ((const float4*)qp)[0], ql1 = ((const float4*)qp)[1];
      float acc[8];
#pragma unroll
      for (int i = 0; i < 8; ++i) acc[i] = 0.f;
#pragma unroll
      for (int j = 0; j < 64; ++j) {
        const float4* hp = (const float4*)&Hq[j][cw * 8];
        float4 h0 = hp[0], h1 = hp[1];
        float cv = cr[j];
        acc[0] = fmaf(cv, h0.x, acc[0]); acc[1] = fmaf(cv, h0.y, acc[1]);
        acc[2] = fmaf(cv, h0.z, acc[2]); acc[3] = fmaf(cv, h0.w, acc[3]);
        acc[4] = fmaf(cv, h1.x, acc[4]); acc[5] = fmaf(cv, h1.y, acc[5]);
        acc[6] = fmaf(cv, h1.z, acc[6]); acc[7] = fmaf(cv, h1.w, acc[7]);
      }
      float4 v0 = make_float4(acc[0] + ql0.x, acc[1] + ql0.y,
                              acc[2] + ql0.z, acc[3] + ql0.w);
      float4 v1 = make_float4(acc[4] + ql1.x, acc[5] + ql1.y,
                              acc[6] + ql1.z, acc[7] + ql1.w);
      __syncthreads();  // all Hq reads done before overwrite
      float4* hw = (float4*)&Hq[63 - t][cw * 8];
      hw[0] = v0;
      hw[1] = v1;
      ((float4*)qp)[0] = v0;
      ((float4*)qp)[1] = v1;
      __syncthreads();
    }
  } else {
    __shared__ __align__(16) float cs2[64][64];
    __shared__ float Hk[64];
    const int s = blockIdx.x - 128;
    const float4* cb = (const float4*)(ct + (long)s * NCH * 4096);
    for (int i = tid; i < 1024; i += 256) ((float4*)cs2)[i] = cb[i];
    if (tid < 64) Hk[tid] = 0.f;
    __syncthreads();
    for (int ch = 0; ch < NCH; ++ch) {
      float acc = 0.f;
      if (tid < 64) {
        acc = klocal[((long)s * NCH + ch) * 64 + tid];
#pragma unroll 8
        for (int j = 0; j < 64; ++j) acc = fmaf(cs2[j][tid], Hk[j], acc);
        kout[s * NT + ch * 64 + tid] = acc;
      }
      __syncthreads();
      if (tid < 64) Hk[63 - tid] = acc;
      if (ch + 1 < NCH)
        for (int i = tid; i < 1024; i += 256)
          ((float4*)cs2)[i] = cb[(ch + 1) * 1024 + i];
      __syncthreads();
    }
  }
}

// K6: rep = (q + 16*anchor)/(k+16) * (k/(k+16)); out = rep_flat @ mix_w + mix_b
__global__ __launch_bounds__(128) void k6_mix(
    const float* __restrict__ q, const float* __restrict__ kout,
    const float* __restrict__ anchor, const float* __restrict__ mixw,
    const float* __restrict__ mixb, float* __restrict__ out) {
  __shared__ float rsdata[8][512];
  const int b = blockIdx.x;
  const int t0 = blockIdx.y * 8;
  const int tid = threadIdx.x;
  for (int i = tid; i < 8 * 512; i += 128) {
    int r = i >> 9, sc = i & 511;
    int s = sc >> 7, c = sc & 127;
    int ti = t0 + r;
    float qv = q[((long)(s * 8 + b) * NT + ti) * NC + c];
    float kv = kout[s * NT + ti];
    float d1 = rcp_fast(kv + 16.f);
    rsdata[r][sc] = (qv + 16.f * anchor[sc]) * d1 * (kv * d1);
  }
  __syncthreads();
  const int co = tid;
  float mb = mixb[co];
  float acc[8];
#pragma unroll
  for (int r = 0; r < 8; ++r) acc[r] = mb;
  for (int kk = 0; kk < 512; ++kk) {
    float w = mixw[kk * 128 + co];
#pragma unroll
    for (int r = 0; r < 8; ++r) acc[r] = fmaf(rsdata[r][kk], w, acc[r]);
  }
#pragma unroll
  for (int r = 0; r < 8; ++r) out[((long)b * NT + t0 + r) * NC + co] = acc[r];
}

extern "C" void kernel_launch(void* const* d_in, const int* in_sizes, int n_in,
                              void* d_out, int out_size, void* d_ws, size_t ws_size,
                              hipStream_t stream) {
  const float* x = (const float*)d_in[0];
  const float* W = (const float*)d_in[1];
  const float* bias = (const float*)d_in[2];
  const float* phiw = (const float*)d_in[3];
  const float* phib = (const float*)d_in[4];
  const float* anchor = (const float*)d_in[5];
  const float* logw = (const float*)d_in[6];
  const float* mixw = (const float*)d_in[7];
  const float* mixb = (const float*)d_in[8];
  float* out = (float*)d_out;

  float* ws = (float*)d_ws;
  float* Q = ws;                                     // 8*2049*128 = 2,098,176
  float* pi = Q + (long)NB * QROWS * NC;             // 4*2048*64  =   524,288
  float* eq = pi + (long)NS * NT * NLM;              // 32*2048*128= 8,388,608
  float* coefT = eq + (long)NS * NB * NT * NC;       // 4*32*64*64 =   524,288
  float* coefTT = coefT + (long)NS * NCH * 4096;     //               524,288
  float* rtb = coefTT + (long)NS * NCH * 4096;       //               524,288
  float* klocal = rtb + (long)NS * NCH * 4096;       //                 8,192
  float* kout = klocal + (long)NS * NCH * 64;        //                 8,192
  float* logZt = kout + (long)NS * NT;               //                 8,196
  float* S2 = logZt + (long)NS * QROWS;              //                32,768

  hipLaunchKernelGGL(k1_uv, dim3(NB * NT / 8), dim3(128), 0, stream, x, W, bias, phiw, Q);
  hipLaunchKernelGGL(k2a_sums, dim3(NB, NCH), dim3(128), 0, stream, Q, S2);
  hipLaunchKernelGGL(k2b_scan, dim3(NB), dim3(128), 0, stream, S2);
  hipLaunchKernelGGL(k2c_fix, dim3(NB, NCH), dim3(128), 0, stream, Q, S2);
  hipLaunchKernelGGL(k3ab_logz, dim3(NS), dim3(64), 0, stream, logw, logZt);
  hipLaunchKernelGGL(k3c_pi, dim3(NT / 4, NS), dim3(256), 0, stream, logw, logZt, pi);
  hipLaunchKernelGGL(k5a_basis, dim3(NS, NCH), dim3(128), 0, stream, pi, rtb, coefT, coefTT, klocal);
  hipLaunchKernelGGL(k4_e, dim3(NB, NT / 32, 2), dim3(256), 0, stream, Q, pi, phib, eq);
  hipLaunchKernelGGL(k5a_data, dim3(NS * NB, NCH), dim3(512), 0, stream, rtb, eq);
  hipLaunchKernelGGL(k5b_scan, dim3(132), dim3(256), 0, stream, coefTT, coefT, klocal, eq, kout);
  hipLaunchKernelGGL(k6_mix, dim3(NB, NT / 8), dim3(128), 0, stream, eq, kout, anchor, mixw, mixb, out);
}

// Round 6
// 479.268 us; speedup vs baseline: 12.3128x; 1.0242x over previous
//
#include <hip/hip_runtime.h>
#include <math.h>

// Problem constants
#define NB 8
#define NT 2048
#define NC 128
#define NLM 64
#define NS 4
#define QROWS 2049
#define NCH 32  // 2048 / 64 chunks

#define TWO_LOG2E 2.885390081777927f

__device__ __forceinline__ float rcp_fast(float x) {
  return __builtin_amdgcn_rcpf(x);
}

__device__ __forceinline__ float readlane_f(float v, int lane) {
  return __int_as_float(__builtin_amdgcn_readlane(__float_as_int(v), lane));
}

// ---------------------------------------------------------------------------
// Tiled 64-step local linear scan (forward substitution); all indices
// compile-time so q[4][16] stays in VGPRs.
// ---------------------------------------------------------------------------
template <typename PF, typename DF>
__device__ __forceinline__ void tri_scan64(PF P, DF D, float q[4][16]) {
#pragma unroll
  for (int tau = 0; tau < 4; ++tau) {
    float acc[16];
#pragma unroll
    for (int i = 0; i < 16; ++i) acc[i] = D(tau * 16 + i);
#pragma unroll
    for (int p = 0; p < 4; ++p) {
      if (p < tau) {
#pragma unroll
        for (int i = 0; i < 16; ++i) {
          const int t = tau * 16 + i;
#pragma unroll
          for (int i2 = 0; i2 < 16; ++i2) {
            acc[i] = fmaf(P(t, t - (p * 16 + i2) - 1), q[p][i2], acc[i]);
          }
        }
      }
    }
#pragma unroll
    for (int i = 0; i < 16; ++i) {
      const int t = tau * 16 + i;
#pragma unroll
      for (int i2 = 0; i2 < 16; ++i2) {
        if (i2 < i) acc[i] = fmaf(P(t, i - i2 - 1), q[tau][i2], acc[i]);
      }
      q[tau][i] = acc[i];
    }
  }
}

// K1: per 8 rows (b,t): z = x@W + b ; u = [cos,sin]/sqrt(dh) ; V = u @ phi_w
__global__ __launch_bounds__(128) void k1_uv(
    const float* __restrict__ x, const float* __restrict__ W,
    const float* __restrict__ bias, const float* __restrict__ phiw,
    float* __restrict__ Q) {
  __shared__ float xs[8][128];
  __shared__ float us[8][256];
  const int j = threadIdx.x;
  const int bt0 = blockIdx.x * 8;
#pragma unroll
  for (int r = 0; r < 8; ++r) xs[r][j] = x[(bt0 + r) * NC + j];
  __syncthreads();
  float z[8];
  const float bj = bias[j];
#pragma unroll
  for (int r = 0; r < 8; ++r) z[r] = bj;
  for (int k = 0; k < 128; ++k) {
    float w = W[k * 128 + j];
#pragma unroll
    for (int r = 0; r < 8; ++r) z[r] = fmaf(xs[r][k], w, z[r]);
  }
  const float rs = 0.08838834764831845f;  // 1/sqrt(128)
#pragma unroll
  for (int r = 0; r < 8; ++r) {
    float sv, cv;
    sincosf(z[r], &sv, &cv);
    us[r][j] = cv * rs;
    us[r][128 + j] = sv * rs;
  }
  __syncthreads();
  float a[8];
#pragma unroll
  for (int r = 0; r < 8; ++r) a[r] = 0.f;
  for (int k = 0; k < 256; ++k) {
    float w = phiw[k * 128 + j];
#pragma unroll
    for (int r = 0; r < 8; ++r) a[r] = fmaf(us[r][k], w, a[r]);
  }
#pragma unroll
  for (int r = 0; r < 8; ++r) {
    int bt = bt0 + r;
    int b = bt >> 11, t = bt & 2047;
    Q[(b * QROWS + t + 1) * NC + j] = a[r];
  }
}

// K2 (chunk-parallel cumsum): a) per-chunk sums, b) per-b scan, c) fixup
__global__ __launch_bounds__(128) void k2a_sums(const float* __restrict__ Q,
                                                float* __restrict__ S2) {
  const int b = blockIdx.x, ch = blockIdx.y, c = threadIdx.x;
  float acc = 0.f;
#pragma unroll 8
  for (int i = 0; i < 64; ++i) acc += Q[(b * QROWS + ch * 64 + 1 + i) * NC + c];
  S2[(b * NCH + ch) * NC + c] = acc;
}

__global__ __launch_bounds__(128) void k2b_scan(float* __restrict__ S2) {
  const int b = blockIdx.x, c = threadIdx.x;
  float acc = 0.f;
  for (int ch = 0; ch < NCH; ++ch) {
    float* p = S2 + (b * NCH + ch) * NC + c;
    float v = *p;
    *p = acc;  // exclusive
    acc += v;
  }
}

__global__ __launch_bounds__(128) void k2c_fix(float* __restrict__ Q,
                                               const float* __restrict__ S2) {
  const int b = blockIdx.x, ch = blockIdx.y, c = threadIdx.x;
  if (ch == 0) Q[(b * QROWS) * NC + c] = 0.f;
  float run = S2[(b * NCH + ch) * NC + c];
#pragma unroll 4
  for (int i = 0; i < 64; ++i) {
    float* p = Q + (b * QROWS + ch * 64 + 1 + i) * NC + c;
    run += *p;
    *p = run;
  }
}

// K3ab fused: unit-response matrix mT of the Z recurrence (LDS) + 32
// sequential chunk-steps of the rescaled linear logZ evolution. Per s.
__global__ __launch_bounds__(64) void k3ab_logz(const float* __restrict__ logw,
                                                float* __restrict__ logZt) {
  const int s = blockIdx.x;
  const int j = threadIdx.x;  // doubles as t in phase 2
  __shared__ float wx[64];
  __shared__ float mTs[64][65];  // [j][t], padded (writes are row-per-lane)
  __shared__ float Zr[64];
  wx[j] = __expf(logw[s * NLM + j]);
  __syncthreads();
  float q[4][16];
  tri_scan64([&](int t, int l) { return wx[l]; },
             [&](int t) { int l = t + j; return (l < 64) ? wx[l] : 0.f; }, q);
#pragma unroll
  for (int tau = 0; tau < 4; ++tau)
#pragma unroll
    for (int i = 0; i < 16; ++i) mTs[j][tau * 16 + i] = q[tau][i];
  // phase 2
  const int t = j;
  Zr[t] = (t == 0) ? 1.f : 0.f;
  if (t == 0) logZt[s * QROWS] = 0.f;
  float off = 0.f;
  __syncthreads();
  for (int ch = 0; ch < NCH; ++ch) {
    float acc = 0.f;
#pragma unroll 8
    for (int jj = 0; jj < 64; ++jj) acc = fmaf(mTs[jj][t], Zr[jj], acc);
    logZt[s * QROWS + ch * 64 + 1 + t] = logf(acc) + off;
    float mx = acc;
#pragma unroll
    for (int o = 32; o; o >>= 1) mx = fmaxf(mx, __shfl_xor(mx, o));
    __syncthreads();
    Zr[63 - t] = acc / mx;
    off += logf(mx);
    __syncthreads();
  }
}

// K3c: pi[s][ti][l] = softmax_l(lw[l] + logZ[ti-l]) — fully parallel.
__global__ __launch_bounds__(256) void k3c_pi(const float* __restrict__ logw,
                                              const float* __restrict__ logZt,
                                              float* __restrict__ pi) {
  const int s = blockIdx.y;
  const int ti = blockIdx.x * 4 + (threadIdx.x >> 6);
  const int l = threadIdx.x & 63;
  float la = -INFINITY;
  if (ti - l >= 0) la = logw[s * NLM + l] + logZt[s * QROWS + ti - l];
  float m = la;
#pragma unroll
  for (int o = 32; o; o >>= 1) m = fmaxf(m, __shfl_xor(m, o));
  float p = __expf(la - m);
  float zs = p;
#pragma unroll
  for (int o = 32; o; o >>= 1) zs += __shfl_xor(zs, o);
  pi[((long)s * NT + ti) * NLM + l] = p * rcp_fast(zs);
}

// K4: e[s,b,ti,c] = 1 - 2 * sum_l pi[s,ti,l] * rcp(exp2(y)+1)
__global__ __launch_bounds__(256) void k4_e(
    const float* __restrict__ Q, const float* __restrict__ pi,
    const float* __restrict__ phib, float* __restrict__ eq) {
  __shared__ float Qw[96][64];                   // 24 KB
  __shared__ __align__(16) float ps[4][32][64];  // 32 KB
  const int b = blockIdx.x;
  const int t0 = blockIdx.y * 32;
  const int half = blockIdx.z;
  const int tid = threadIdx.x;
  for (int i = tid; i < 96 * 64; i += 256) {
    int r = i >> 6, cc = i & 63;
    int tau = t0 - 63 + r;
    Qw[r][cc] = (tau >= 0) ? Q[(b * QROWS + tau) * NC + half * 64 + cc] : 0.f;
  }
  for (int i = tid; i < 2048; i += 256) {  // 2048 float4 = 4 scales x 512
    int s = i >> 9, rem = i & 511;
    ((float4*)ps)[i] = ((const float4*)(pi + ((long)s * NT + t0) * NLM))[rem];
  }
  __syncthreads();
  const int c = tid & 63, tg = tid >> 6;  // tg wave-uniform
  const float pb2 = phib[half * 64 + c] * TWO_LOG2E;
  for (int tt = tg; tt < 32; tt += 4) {
    const int ti = t0 + tt;
    const float Qt = Qw[tt + 64][c];
    float a0 = 0.f, a1 = 0.f, a2 = 0.f, a3 = 0.f;
#pragma unroll
    for (int l = 0; l < 64; l += 4) {
      float v[4];
#pragma unroll
      for (int u = 0; u < 4; ++u) {
        const float cl = TWO_LOG2E / (float)(l + u + 9);  // folded constant
        float y = (Qt - Qw[tt + 63 - (l + u)][c]) * cl + pb2;
        v[u] = rcp_fast(__builtin_exp2f(y) + 1.f);
      }
      float4 w0 = *(const float4*)&ps[0][tt][l];
      float4 w1 = *(const float4*)&ps[1][tt][l];
      float4 w2 = *(const float4*)&ps[2][tt][l];
      float4 w3 = *(const float4*)&ps[3][tt][l];
      a0 = fmaf(w0.x, v[0], a0); a0 = fmaf(w0.y, v[1], a0);
      a0 = fmaf(w0.z, v[2], a0); a0 = fmaf(w0.w, v[3], a0);
      a1 = fmaf(w1.x, v[0], a1); a1 = fmaf(w1.y, v[1], a1);
      a1 = fmaf(w1.z, v[2], a1); a1 = fmaf(w1.w, v[3], a1);
      a2 = fmaf(w2.x, v[0], a2); a2 = fmaf(w2.y, v[1], a2);
      a2 = fmaf(w2.z, v[2], a2); a2 = fmaf(w2.w, v[3], a2);
      a3 = fmaf(w3.x, v[0], a3); a3 = fmaf(w3.y, v[1], a3);
      a3 = fmaf(w3.z, v[2], a3); a3 = fmaf(w3.w, v[3], a3);
    }
    const long base = half * 64 + c;
    eq[((long)(0 * 8 + b) * NT + ti) * NC + base] = fmaf(-2.f, a0, 1.f);
    eq[((long)(1 * 8 + b) * NT + ti) * NC + base] = fmaf(-2.f, a1, 1.f);
    eq[((long)(2 * 8 + b) * NT + ti) * NC + base] = fmaf(-2.f, a2, 1.f);
    eq[((long)(3 * 8 + b) * NT + ti) * NC + base] = fmaf(-2.f, a3, 1.f);
  }
}

// K5a-basis (per s,ch): threads 0..63: impulse-response columns R (rt, [tp][t]);
// threads 64..127: history responses ctT ([t][j]); klocal = row sums of R.
__global__ __launch_bounds__(128) void k5a_basis(const float* __restrict__ pi,
                                                 float* __restrict__ rt,
                                                 float* __restrict__ ctT,
                                                 float* __restrict__ klocal) {
  __shared__ __align__(16) float psd[4096];
  __shared__ float Rl[64][65];
  const int s = blockIdx.x, ch = blockIdx.y;
  const int tid = threadIdx.x;
  const float* pib = pi + ((long)s * NT + ch * 64) * NLM;
  for (int i = tid; i < 1024; i += 128) ((float4*)psd)[i] = ((const float4*)pib)[i];
  __syncthreads();
  float q[4][16];
  if (tid < 64) {
    const int tp = tid;  // impulse position
    tri_scan64([&](int t, int l) { return psd[t * 64 + l]; },
               [&](int t) { return (t == tp) ? 1.f : 0.f; }, q);
    float* rrow = rt + (((long)s * NCH + ch) * 64 + tp) * 64;  // [tp][t]
#pragma unroll
    for (int tau = 0; tau < 4; ++tau)
#pragma unroll
      for (int i = 0; i < 16; ++i) {
        rrow[tau * 16 + i] = q[tau][i];
        Rl[tp][tau * 16 + i] = q[tau][i];
      }
  } else {
    const int j = tid - 64;  // history lookback j+1
    tri_scan64([&](int t, int l) { return psd[t * 64 + l]; },
               [&](int t) { int l = t + j; return (l < 64) ? psd[t * 64 + l] : 0.f; }, q);
    float* ctb = ctT + ((long)s * NCH + ch) * 4096;  // [t][j]
#pragma unroll
    for (int tau = 0; tau < 4; ++tau)
#pragma unroll
      for (int i = 0; i < 16; ++i) ctb[(tau * 16 + i) * 64 + j] = q[tau][i];
  }
  __syncthreads();
  if (tid < 64) {  // klocal[t] = sum_t' R[t][t']
    float acc = 0.f;
#pragma unroll 8
    for (int tp = 0; tp < 64; ++tp) acc += Rl[tp][tid];
    klocal[((long)s * NCH + ch) * 64 + tid] = acc;
  }
}

// K5a-data: qlocal = R @ e per (s,b,chunk) — tiled GEMM, 8t x 8c per lane.
__global__ __launch_bounds__(128) void k5a_data(const float* __restrict__ rt,
                                                float* __restrict__ eq) {
  __shared__ __align__(16) float rts[4096];    // [tp][t] 16 KB
  __shared__ __align__(16) float es[64][128];  // 32 KB
  const int sb = blockIdx.x;  // s*8+b
  const int s = sb >> 3;
  const int ch = blockIdx.y;
  const int tid = threadIdx.x;
  const float4* rsrc = (const float4*)(rt + ((long)s * NCH + ch) * 4096);
#pragma unroll
  for (int i = 0; i < 8; ++i) ((float4*)rts)[tid + 128 * i] = rsrc[tid + 128 * i];
  float* qb = eq + ((long)sb * NT + ch * 64) * NC;
  const float4* esrc = (const float4*)qb;
#pragma unroll
  for (int i = 0; i < 16; ++i) ((float4*)es)[tid + 128 * i] = esrc[tid + 128 * i];
  __syncthreads();
  const int t0 = (tid >> 4) * 8;  // 8 t-tiles
  const int c0 = (tid & 15) * 8;  // 16 c-tiles
  float acc[8][8];
#pragma unroll
  for (int i = 0; i < 8; ++i)
#pragma unroll
    for (int k = 0; k < 8; ++k) acc[i][k] = 0.f;
  for (int tp = 0; tp < 64; ++tp) {
    if (tp <= t0 + 7) {  // R is lower-triangular: R[t][tp]=0 for tp>t
      float4 r0 = *(const float4*)&rts[tp * 64 + t0];
      float4 r1 = *(const float4*)&rts[tp * 64 + t0 + 4];
      float4 e0 = *(const float4*)&es[tp][c0];
      float4 e1 = *(const float4*)&es[tp][c0 + 4];
      float rr[8] = {r0.x, r0.y, r0.z, r0.w, r1.x, r1.y, r1.z, r1.w};
      float ee[8] = {e0.x, e0.y, e0.z, e0.w, e1.x, e1.y, e1.z, e1.w};
#pragma unroll
      for (int i = 0; i < 8; ++i)
#pragma unroll
        for (int k = 0; k < 8; ++k) acc[i][k] = fmaf(rr[i], ee[k], acc[i][k]);
    }
  }
#pragma unroll
  for (int i = 0; i < 8; ++i) {
    float4* dst = (float4*)(qb + (t0 + i) * NC + c0);
    dst[0] = make_float4(acc[i][0], acc[i][1], acc[i][2], acc[i][3]);
    dst[1] = make_float4(acc[i][4], acc[i][5], acc[i][6], acc[i][7]);
  }
}

// K5b: cross-chunk combine with NO LDS: history lives in the wave's own
// registers (lane t holds q[t] of the previous chunk); H[j] is fetched via
// v_readlane (compile-time lane 63-j, SGPR feeds fma directly). Coef rows
// double-buffered in VGPRs (crA/crB) so the 16 global b128 loads hide under
// the j-loop. Blocks 0..511: q (sb x 16 slices of 8 channels); 512..515: k.
__global__ __launch_bounds__(64) void k5b_scan(const float* __restrict__ ctT,
                                               const float* __restrict__ klocal,
                                               float* __restrict__ eq,
                                               float* __restrict__ kout) {
  const int t = threadIdx.x;
  if (blockIdx.x < 512) {
    const int sb = blockIdx.x >> 4, sl = blockIdx.x & 15;
    const int s = sb >> 3;
    const int c0 = sl * 8;
    const float* ctTs = ctT + (long)s * NCH * 4096 + t * 64;
    float4 crA[16], crB[16];
    {
      const float4* p = (const float4*)ctTs;
#pragma unroll
      for (int i = 0; i < 16; ++i) crA[i] = p[i];
    }
    float hv[8];
#pragma unroll
    for (int i = 0; i < 8; ++i) hv[i] = 0.f;
    float* eqb = eq + (long)sb * NT * NC + c0;

#define K5B_BODY(CH, CR)                                                     \
    {                                                                        \
      float* qp = eqb + ((CH) * 64 + t) * NC;                                \
      float4 ql0 = ((const float4*)qp)[0], ql1 = ((const float4*)qp)[1];     \
      float acc[8];                                                          \
      _Pragma("unroll") for (int i = 0; i < 8; ++i) acc[i] = 0.f;            \
      const float* cr = (const float*)(CR);                                  \
      _Pragma("unroll") for (int j = 0; j < 64; ++j) {                       \
        float cv = cr[j];                                                    \
        _Pragma("unroll") for (int i = 0; i < 8; ++i)                        \
            acc[i] = fmaf(cv, readlane_f(hv[i], 63 - j), acc[i]);            \
      }                                                                      \
      hv[0] = acc[0] + ql0.x; hv[1] = acc[1] + ql0.y;                        \
      hv[2] = acc[2] + ql0.z; hv[3] = acc[3] + ql0.w;                        \
      hv[4] = acc[4] + ql1.x; hv[5] = acc[5] + ql1.y;                        \
      hv[6] = acc[6] + ql1.z; hv[7] = acc[7] + ql1.w;                        \
      ((float4*)qp)[0] = make_float4(hv[0], hv[1], hv[2], hv[3]);            \
      ((float4*)qp)[1] = make_float4(hv[4], hv[5], hv[6], hv[7]);            \
    }

#pragma unroll 1
    for (int ch = 0; ch < NCH; ch += 2) {
      {
        const float4* p = (const float4*)(ctTs + (ch + 1) * 4096);
#pragma unroll
        for (int i = 0; i < 16; ++i) crB[i] = p[i];
      }
      K5B_BODY(ch, crA)
      if (ch + 2 < NCH) {
        const float4* p = (const float4*)(ctTs + (ch + 2) * 4096);
#pragma unroll
        for (int i = 0; i < 16; ++i) crA[i] = p[i];
      }
      K5B_BODY(ch + 1, crB)
    }
#undef K5B_BODY
  } else {
    const int s = blockIdx.x - 512;
    const float* ctTs = ctT + (long)s * NCH * 4096 + t * 64;
    float4 crA[16], crB[16];
    {
      const float4* p = (const float4*)ctTs;
#pragma unroll
      for (int i = 0; i < 16; ++i) crA[i] = p[i];
    }
    float hk = 0.f;

#define K5BK_BODY(CH, CR)                                                    \
    {                                                                        \
      float acc = klocal[((long)s * NCH + (CH)) * 64 + t];                   \
      const float* cr = (const float*)(CR);                                  \
      _Pragma("unroll") for (int j = 0; j < 64; ++j)                         \
          acc = fmaf(cr[j], readlane_f(hk, 63 - j), acc);                    \
      kout[s * NT + (CH) * 64 + t] = acc;                                    \
      hk = acc;                                                              \
    }

#pragma unroll 1
    for (int ch = 0; ch < NCH; ch += 2) {
      {
        const float4* p = (const float4*)(ctTs + (ch + 1) * 4096);
#pragma unroll
        for (int i = 0; i < 16; ++i) crB[i] = p[i];
      }
      K5BK_BODY(ch, crA)
      if (ch + 2 < NCH) {
        const float4* p = (const float4*)(ctTs + (ch + 2) * 4096);
#pragma unroll
        for (int i = 0; i < 16; ++i) crA[i] = p[i];
      }
      K5BK_BODY(ch + 1, crB)
    }
#undef K5BK_BODY
  }
}

// K6: rep = (q + 16*anchor)/(k+16) * (k/(k+16)); out = rep_flat @ mix_w + mix_b
__global__ __launch_bounds__(128) void k6_mix(
    const float* __restrict__ q, const float* __restrict__ kout,
    const float* __restrict__ anchor, const float* __restrict__ mixw,
    const float* __restrict__ mixb, float* __restrict__ out) {
  __shared__ __align__(16) float rsdata[8][512];
  const int b = blockIdx.x;
  const int t0 = blockIdx.y * 8;
  const int tid = threadIdx.x;
  for (int i = tid; i < 8 * 512; i += 128) {
    int r = i >> 9, sc = i & 511;
    int s = sc >> 7, c = sc & 127;
    int ti = t0 + r;
    float qv = q[((long)(s * 8 + b) * NT + ti) * NC + c];
    float kv = kout[s * NT + ti];
    float d1 = rcp_fast(kv + 16.f);
    rsdata[r][sc] = (qv + 16.f * anchor[sc]) * d1 * (kv * d1);
  }
  __syncthreads();
  const int co = tid;
  float mb = mixb[co];
  float acc[8];
#pragma unroll
  for (int r = 0; r < 8; ++r) acc[r] = mb;
  for (int kk = 0; kk < 512; kk += 4) {
    float wa = mixw[(kk + 0) * 128 + co];
    float wb = mixw[(kk + 1) * 128 + co];
    float wc = mixw[(kk + 2) * 128 + co];
    float wd = mixw[(kk + 3) * 128 + co];
#pragma unroll
    for (int r = 0; r < 8; ++r) {
      float4 rv = *(const float4*)&rsdata[r][kk];
      acc[r] = fmaf(rv.x, wa, acc[r]);
      acc[r] = fmaf(rv.y, wb, acc[r]);
      acc[r] = fmaf(rv.z, wc, acc[r]);
      acc[r] = fmaf(rv.w, wd, acc[r]);
    }
  }
#pragma unroll
  for (int r = 0; r < 8; ++r) out[((long)b * NT + t0 + r) * NC + co] = acc[r];
}

extern "C" void kernel_launch(void* const* d_in, const int* in_sizes, int n_in,
                              void* d_out, int out_size, void* d_ws, size_t ws_size,
                              hipStream_t stream) {
  const float* x = (const float*)d_in[0];
  const float* W = (const float*)d_in[1];
  const float* bias = (const float*)d_in[2];
  const float* phiw = (const float*)d_in[3];
  const float* phib = (const float*)d_in[4];
  const float* anchor = (const float*)d_in[5];
  const float* logw = (const float*)d_in[6];
  const float* mixw = (const float*)d_in[7];
  const float* mixb = (const float*)d_in[8];
  float* out = (float*)d_out;

  float* ws = (float*)d_ws;
  float* Q = ws;                                     // 8*2049*128 = 2,098,176
  float* pi = Q + (long)NB * QROWS * NC;             // 4*2048*64  =   524,288
  float* eq = pi + (long)NS * NT * NLM;              // 32*2048*128= 8,388,608
  float* coefTT = eq + (long)NS * NB * NT * NC;      //               524,288
  float* rtb = coefTT + (long)NS * NCH * 4096;       //               524,288
  float* klocal = rtb + (long)NS * NCH * 4096;       //                 8,192
  float* kout = klocal + (long)NS * NCH * 64;        //                 8,192
  float* logZt = kout + (long)NS * NT;               //                 8,196
  float* S2 = logZt + (long)NS * QROWS;              //                32,768

  hipLaunchKernelGGL(k1_uv, dim3(NB * NT / 8), dim3(128), 0, stream, x, W, bias, phiw, Q);
  hipLaunchKernelGGL(k2a_sums, dim3(NB, NCH), dim3(128), 0, stream, Q, S2);
  hipLaunchKernelGGL(k2b_scan, dim3(NB), dim3(128), 0, stream, S2);
  hipLaunchKernelGGL(k2c_fix, dim3(NB, NCH), dim3(128), 0, stream, Q, S2);
  hipLaunchKernelGGL(k3ab_logz, dim3(NS), dim3(64), 0, stream, logw, logZt);
  hipLaunchKernelGGL(k3c_pi, dim3(NT / 4, NS), dim3(256), 0, stream, logw, logZt, pi);
  hipLaunchKernelGGL(k5a_basis, dim3(NS, NCH), dim3(128), 0, stream, pi, rtb, coefTT, klocal);
  hipLaunchKernelGGL(k4_e, dim3(NB, NT / 32, 2), dim3(256), 0, stream, Q, pi, phib, eq);
  hipLaunchKernelGGL(k5a_data, dim3(NS * NB, NCH), dim3(128), 0, stream, rtb, eq);
  hipLaunchKernelGGL(k5b_scan, dim3(516), dim3(64), 0, stream, coefTT, klocal, eq, kout);
  hipLaunchKernelGGL(k6_mix, dim3(NB, NT / 8), dim3(128), 0, stream, eq, kout, anchor, mixw, mixb, out);
}